// Round 10
// baseline (219.126 us; speedup 1.0000x reference)
//
#include <hip/hip_runtime.h>
#include <hip/hip_bf16.h>

#define N_NODES 100000
#define N_EDGES 1000000
#define EMB 64
#define HID 64
#define VOCAB 128
#define N_GRAPHS 2048

#define S_BLOCKS 1024                                  // scatter grid-stride blocks
#define GB ((N_NODES + 255) / 256)                     // 391 gstart blocks
#define NB1 ((N_NODES + 127) / 128)                    // 782 sage1 blocks
#define NPAD 100128                                    // node arrays padded to x128
#define OVF_CAP 65536
#define ZROW 0x1FFFF                                   // dummy row index in p8

#define BCASTF(v, l) __int_as_float(__builtin_amdgcn_readlane(__float_as_int(v), (l)))

typedef __attribute__((ext_vector_type(8))) short short8;
typedef __attribute__((ext_vector_type(4))) float f32x4;
typedef __attribute__((ext_vector_type(2))) float f32x2;

__device__ __forceinline__ float bf2f(unsigned short u) {
    return __uint_as_float((unsigned)u << 16);
}
__device__ __forceinline__ float bf2f_lo(unsigned u) {
    return __uint_as_float(u << 16);
}
__device__ __forceinline__ float bf2f_hi(unsigned u) {
    return __uint_as_float(u & 0xffff0000u);
}
__device__ __forceinline__ unsigned short f2bf(float f) {
    return __bfloat16_as_ushort(__float2bfloat16(f));
}

// ---- scatter: direct col32 slotting (no edge8, no CSR kernel) -----------
//   [0,1024): grid-stride edges: slot=atomicAdd(deg[d]); col32[d][slot]=s|x<<17
//             (slot>=32 -> tiny overflow list; Poisson(10) => ~never)
//   [1024,1415): gstart boundaries
//   [1415,1447): w1frag DIRECT write (embW1 row (v,n) -> fragment slot),
//                w2frag pack, p8 dummy-row zero
__global__ __launch_bounds__(256) void scatter_kernel(
    const int* __restrict__ src, const int* __restrict__ dst,
    const int* __restrict__ x,
    int* __restrict__ dcnt, int* __restrict__ col32,
    int2* __restrict__ ovf, int* __restrict__ ovf_cnt,
    const int* __restrict__ batch, int* __restrict__ gstart,
    const float* __restrict__ emb, const float* __restrict__ W1l,
    const float* __restrict__ W1r,
    const float* __restrict__ W2l, const float* __restrict__ W2r,
    unsigned short* __restrict__ w1frag, unsigned short* __restrict__ w2frag,
    unsigned char* __restrict__ p8z)
{
    int b = blockIdx.x;
    int t = threadIdx.x;

    if (b < S_BLOCKS) {
        for (int i = b * 256 + t; i < N_EDGES; i += S_BLOCKS * 256) {
            int d = dst[i];
            int s = src[i];
            int xv = x[s];                       // random 4B read, 400KB L2-hot
            int pay = s | (xv << 17);
            int slot = atomicAdd(&dcnt[d], 1);
            if (slot < 32) {
                col32[(size_t)d * 32 + slot] = pay;
            } else {
                int w = atomicAdd(ovf_cnt, 1);
                if (w < OVF_CAP) ovf[w] = make_int2(d, pay);
            }
        }
    } else if (b < S_BLOCKS + GB) {
        // ---- graph boundaries (batch sorted)
        int i = (b - S_BLOCKS) * 256 + t;
        if (i >= N_NODES) return;
        int bg = batch[i];
        int bp = (i == 0) ? -1 : batch[i - 1];
        for (int g = bp + 1; g <= bg; ++g) gstart[g] = i;
        if (i == N_NODES - 1)
            for (int g = bg + 1; g <= N_GRAPHS; ++g) gstart[g] = N_NODES;
    } else {
        int vb = b - S_BLOCKS - GB;              // 0..31
        // dummy row for sage2's branch-free gather (fp8 0x00 == +0.0)
        if (vb == 0 && t < 16)
            ((unsigned*)(p8z + (size_t)ZROW * 64))[t] = 0u;

        int wave = t >> 6, lane = t & 63;
        int v = vb * 4 + wave;                   // 0..127
        {
            float er = emb[v * 64 + lane];       // lane = d
            float al = 0.f, ar = 0.f;
#pragma unroll 8
            for (int d = 0; d < 64; ++d) {
                float e = BCASTF(er, d);
                al += e * W1l[d * 64 + lane];
                ar += e * W1r[d * 64 + lane];
            }
            // direct w1frag write: value B[kg][n], kg=v (left) / 128+v (right),
            // n=lane. Fragment slot: kf=kg>>5, l=((kg>>3)&3)<<4 | (n&15),
            // nt=n>>4, j=kg&7 -> g=((kf*4+nt)*64+l)*8+j  (matches old packer)
            int reml = (v >> 3) & 3, jj = v & 7;
            int ll = (reml << 4) | (lane & 15);
            int nt = lane >> 4;
            int gl = ((((v >> 5)) * 4 + nt) * 64 + ll) * 8 + jj;
            int gr = ((((v >> 5) + 4) * 4 + nt) * 64 + ll) * 8 + jj;
            w1frag[gl] = f2bf(al);
            w1frag[gr] = f2bf(ar);
        }
        // W2 B-fragment packing: g = tt*1024 + h*512 + l*8 + j
        int g = vb * 256 + t;
        int j = g & 7, l = (g >> 3) & 63, h = (g >> 9) & 1, tt = g >> 10;
        int k = h * 32 + ((l >> 4) * 8) + j;
        int n = tt * 16 + (l & 15);
        float w = (n < 64) ? W2l[k * 64 + n] : W2r[k * 64 + (n - 64)];
        w2frag[g] = f2bf(w);
    }
}

// ---- sage1, histogram-MFMA form, sourced from col32 ---------------------
//   One block per 128 nodes: hist built from the block's contiguous col32
//   region (16 KB coalesced), one LDS packed-add per edge. Overflow list
//   (deg>32, ~empty) scanned for completeness. MFMA phases unchanged.
__global__ __launch_bounds__(256) void sage1_kernel(
    const int* __restrict__ x, const int* __restrict__ deg,
    const int* __restrict__ col32,
    const int2* __restrict__ ovf, const int* __restrict__ ovf_cnt,
    const unsigned short* __restrict__ w1frag,
    const unsigned short* __restrict__ w2frag, const float* __restrict__ b1,
    unsigned char* __restrict__ p8, unsigned short* __restrict__ q16)
{
    __shared__ unsigned hist[128 * 32];         // 16 KB u8[128][128], swizzled words
    __shared__ unsigned short msbuf[128 * 72];  // 18 KB h1 bf16, stride 72
    __shared__ int xl[128];
    __shared__ int degl[128];
    __shared__ float invd[128];

    int blk = blockIdx.x;
    int t = threadIdx.x;
    int nbase = blk * 128;

    for (int i = t * 4; i < 128 * 32; i += 1024)
        *(uint4*)&hist[i] = (uint4){0u, 0u, 0u, 0u};
    if (t < 128) {
        int node = nbase + t;
        int dv = deg[node];                     // padded+zeroed alloc
        degl[t] = dv;
        invd[t] = 1.0f / fmaxf((float)dv, 1.0f);
        xl[t] = (node < N_NODES) ? x[node] : 0;
    }
    __syncthreads();

    // hist from col32: 4096 slots, coalesced reads, validity j < deg
    for (int i = t; i < 128 * 32; i += 256) {
        int r = i >> 5, j = i & 31;
        if (j < degl[r]) {
            unsigned e = (unsigned)col32[(size_t)(nbase + r) * 32 + j];
            int xv = (int)((e >> 17) & 127);
            int wc = (xv >> 2) ^ ((r & 7) << 2);        // word swizzle
            atomicAdd(&hist[r * 32 + wc], 1u << ((xv & 3) * 8));
        }
    }
    // overflow edges (deg>32), near-empty
    int ovn = *ovf_cnt; if (ovn > OVF_CAP) ovn = OVF_CAP;
    for (int k = t; k < ovn; k += 256) {
        int2 e = ovf[k];
        int r = e.x - nbase;
        if (r >= 0 && r < 128) {
            int xv = (e.y >> 17) & 127;
            int wc = (xv >> 2) ^ ((r & 7) << 2);
            atomicAdd(&hist[r * 32 + wc], 1u << ((xv & 3) * 8));
        }
    }
    __syncthreads();

    int wave = t >> 6, lane = t & 63;
    int m = lane & 15;                  // A row / C col index
    int qd = lane >> 4;                 // k-subchunk / C row-group
    int hswz = (m & 7) << 2;            // row m's word swizzle

#pragma unroll
    for (int rt = wave * 2; rt < wave * 2 + 2; ++rt) {
        short8 acnt[4], aself[4];
#pragma unroll
        for (int kf = 0; kf < 4; ++kf) {
            int w0 = (kf * 8 + qd * 2) ^ hswz;
            uint2 u = *(const uint2*)&hist[(rt * 16 + m) * 32 + w0];
            short8 f;
            f[0] = (short)f2bf((float)(u.x & 255));
            f[1] = (short)f2bf((float)((u.x >> 8) & 255));
            f[2] = (short)f2bf((float)((u.x >> 16) & 255));
            f[3] = (short)f2bf((float)(u.x >> 24));
            f[4] = (short)f2bf((float)(u.y & 255));
            f[5] = (short)f2bf((float)((u.y >> 8) & 255));
            f[6] = (short)f2bf((float)((u.y >> 16) & 255));
            f[7] = (short)f2bf((float)(u.y >> 24));
            acnt[kf] = f;
        }
        int xv = xl[rt * 16 + m];
#pragma unroll
        for (int kf = 0; kf < 4; ++kf) {
            int v = xv - kf * 32 - qd * 8;
            short8 f;
#pragma unroll
            for (int j = 0; j < 8; ++j)
                f[j] = (v == j) ? (short)0x3F80 : (short)0;
            aself[kf] = f;
        }
        float iv0 = invd[rt * 16 + qd * 4 + 0];
        float iv1 = invd[rt * 16 + qd * 4 + 1];
        float iv2 = invd[rt * 16 + qd * 4 + 2];
        float iv3 = invd[rt * 16 + qd * 4 + 3];

#pragma unroll
        for (int nt = 0; nt < 4; ++nt) {
            f32x4 accA = {0.f, 0.f, 0.f, 0.f};
            f32x4 accS = {0.f, 0.f, 0.f, 0.f};
#pragma unroll
            for (int kf = 0; kf < 4; ++kf) {
                short8 bA = *(const short8*)(w1frag + ((kf * 4 + nt) * 64 + lane) * 8);
                accA = __builtin_amdgcn_mfma_f32_16x16x32_bf16(acnt[kf], bA, accA, 0, 0, 0);
            }
#pragma unroll
            for (int kf = 0; kf < 4; ++kf) {
                short8 bS = *(const short8*)(w1frag + (((kf + 4) * 4 + nt) * 64 + lane) * 8);
                accS = __builtin_amdgcn_mfma_f32_16x16x32_bf16(aself[kf], bS, accS, 0, 0, 0);
            }
            int c = nt * 16 + m;
            float b1c = b1[c];
            int rb = rt * 16 + qd * 4;
            msbuf[(rb + 0) * 72 + c] = f2bf(fmaxf(accA[0] * iv0 + accS[0] + b1c, 0.f));
            msbuf[(rb + 1) * 72 + c] = f2bf(fmaxf(accA[1] * iv1 + accS[1] + b1c, 0.f));
            msbuf[(rb + 2) * 72 + c] = f2bf(fmaxf(accA[2] * iv2 + accS[2] + b1c, 0.f));
            msbuf[(rb + 3) * 72 + c] = f2bf(fmaxf(accA[3] * iv3 + accS[3] + b1c, 0.f));
        }
    }
    __syncthreads();

#pragma unroll
    for (int rt = wave * 2; rt < wave * 2 + 2; ++rt) {
        const unsigned short* arow = &msbuf[(rt * 16 + m) * 72 + qd * 8];
        short8 a0 = *(const short8*)(arow);
        short8 a1 = *(const short8*)(arow + 32);
        int rowb = nbase + rt * 16 + qd * 4;

#pragma unroll
        for (int tt = 0; tt < 8; ++tt) {
            short8 b0 = *(const short8*)(w2frag + tt * 1024 + lane * 8);
            short8 b1v = *(const short8*)(w2frag + tt * 1024 + 512 + lane * 8);
            f32x4 acc = {0.f, 0.f, 0.f, 0.f};
            acc = __builtin_amdgcn_mfma_f32_16x16x32_bf16(a0, b0, acc, 0, 0, 0);
            acc = __builtin_amdgcn_mfma_f32_16x16x32_bf16(a1, b1v, acc, 0, 0, 0);
            int o = tt * 16 + m;
            if (o < 64) {
                int pk01 = __builtin_amdgcn_cvt_pk_fp8_f32(acc[0], acc[1], 0, false);
                int pk23 = __builtin_amdgcn_cvt_pk_fp8_f32(acc[2], acc[3], 0, false);
                if (rowb + 0 < N_NODES) p8[(rowb + 0) * 64 + o] = (unsigned char)(pk01 & 0xff);
                if (rowb + 1 < N_NODES) p8[(rowb + 1) * 64 + o] = (unsigned char)((pk01 >> 8) & 0xff);
                if (rowb + 2 < N_NODES) p8[(rowb + 2) * 64 + o] = (unsigned char)(pk23 & 0xff);
                if (rowb + 3 < N_NODES) p8[(rowb + 3) * 64 + o] = (unsigned char)((pk23 >> 8) & 0xff);
            } else {
                int oc = o & 63;
#pragma unroll
                for (int i = 0; i < 4; ++i)
                    if (rowb + i < N_NODES)
                        q16[(rowb + i) * 64 + oc] = f2bf(acc[i]);
            }
        }
    }
}

// ---- sage2: round-9 asm gather retargeted at col32. Garbage slots (j>=deg)
//   replaced by the dummy row via cndmask (no col32 init). Tail 16..31 reads
//   col32 directly; deg>32 falls back to the overflow list (near-empty).
#define S2_NPW 8
__global__ __launch_bounds__(256) void sage2_kernel(
    const unsigned char* __restrict__ p, const unsigned short* __restrict__ q,
    const int* __restrict__ deg, const int* __restrict__ col32,
    const int2* __restrict__ ovf, const int* __restrict__ ovf_cnt,
    const float* __restrict__ b2,
    const float* __restrict__ Wout, const int* __restrict__ batch,
    float* __restrict__ gsum)
{
    int t = threadIdx.x;
    int wave = t >> 6, lane = t & 63;
    int base_node = (blockIdx.x * 4 + wave) * S2_NPW;   // exact cover
    int c = lane & 15;          // feature quad: features 4c..4c+3
    int g = lane >> 4;          // row group 0..3

    float4 b2v = ((const float4*)b2)[c];
    float4 w01 = ((const float4*)Wout)[c * 2];
    float4 w23 = ((const float4*)Wout)[c * 2 + 1];

    int dgs[S2_NPW];
#pragma unroll
    for (int n = 0; n < S2_NPW; ++n)
        dgs[n] = deg[base_node + n];

#define ACC(a, v) { f32x2 f01_ = __builtin_amdgcn_cvt_pk_f32_fp8((int)(v), false); \
                    f32x2 f23_ = __builtin_amdgcn_cvt_pk_f32_fp8((int)(v), true);  \
                    (a).x += f01_.x; (a).y += f01_.y; (a).z += f23_.x; (a).w += f23_.y; }

#pragma unroll
    for (int hb = 0; hb < 2; ++hb) {
        int nb = hb * 4;                        // nodes base_node+nb .. +nb+3

        // ---- asm block 1: 16 idx loads from col32, offset nn*128 + k*16 ----
        unsigned vc = (unsigned)((base_node + nb) * 128 + g * 4);
        unsigned i00, i01, i02, i03, i10, i11, i12, i13;
        unsigned i20, i21, i22, i23, i30, i31, i32, i33;
        asm volatile(
            "global_load_dword %0,  %16, %17\n\t"
            "global_load_dword %1,  %16, %17 offset:16\n\t"
            "global_load_dword %2,  %16, %17 offset:32\n\t"
            "global_load_dword %3,  %16, %17 offset:48\n\t"
            "global_load_dword %4,  %16, %17 offset:128\n\t"
            "global_load_dword %5,  %16, %17 offset:144\n\t"
            "global_load_dword %6,  %16, %17 offset:160\n\t"
            "global_load_dword %7,  %16, %17 offset:176\n\t"
            "global_load_dword %8,  %16, %17 offset:256\n\t"
            "global_load_dword %9,  %16, %17 offset:272\n\t"
            "global_load_dword %10, %16, %17 offset:288\n\t"
            "global_load_dword %11, %16, %17 offset:304\n\t"
            "global_load_dword %12, %16, %17 offset:384\n\t"
            "global_load_dword %13, %16, %17 offset:400\n\t"
            "global_load_dword %14, %16, %17 offset:416\n\t"
            "global_load_dword %15, %16, %17 offset:432\n\t"
            "s_waitcnt vmcnt(0)"
            : "=&v"(i00), "=&v"(i01), "=&v"(i02), "=&v"(i03),
              "=&v"(i10), "=&v"(i11), "=&v"(i12), "=&v"(i13),
              "=&v"(i20), "=&v"(i21), "=&v"(i22), "=&v"(i23),
              "=&v"(i30), "=&v"(i31), "=&v"(i32), "=&v"(i33)
            : "v"(vc), "s"(col32)
            : "memory");

        // ---- validity select (slot j = k*4+g vs deg) + x-bit mask ----
        unsigned cc4 = (unsigned)(c << 2);
        int d0 = dgs[nb + 0], d1 = dgs[nb + 1], d2 = dgs[nb + 2], d3 = dgs[nb + 3];
#define SEL(i_, dg_, k_) ((((k_) * 4 + g) < (dg_)) ? ((i_) & 0x1FFFFu) : (unsigned)ZROW)
        unsigned o00 = (SEL(i00, d0, 0) << 6) + cc4, o01 = (SEL(i01, d0, 1) << 6) + cc4;
        unsigned o02 = (SEL(i02, d0, 2) << 6) + cc4, o03 = (SEL(i03, d0, 3) << 6) + cc4;
        unsigned o10 = (SEL(i10, d1, 0) << 6) + cc4, o11 = (SEL(i11, d1, 1) << 6) + cc4;
        unsigned o12 = (SEL(i12, d1, 2) << 6) + cc4, o13 = (SEL(i13, d1, 3) << 6) + cc4;
        unsigned o20 = (SEL(i20, d2, 0) << 6) + cc4, o21 = (SEL(i21, d2, 1) << 6) + cc4;
        unsigned o22 = (SEL(i22, d2, 2) << 6) + cc4, o23 = (SEL(i23, d2, 3) << 6) + cc4;
        unsigned o30 = (SEL(i30, d3, 0) << 6) + cc4, o31 = (SEL(i31, d3, 1) << 6) + cc4;
        unsigned o32 = (SEL(i32, d3, 2) << 6) + cc4, o33 = (SEL(i33, d3, 3) << 6) + cc4;
#undef SEL
        unsigned vq = (unsigned)((base_node + nb) * 128 + c * 8);

        // ---- asm block 2: 16 p-gathers + 8 q-dwords, one waitcnt ----
        unsigned v00, v01, v02, v03, v10, v11, v12, v13;
        unsigned v20, v21, v22, v23, v30, v31, v32, v33;
        unsigned qa0, qb0, qa1, qb1, qa2, qb2, qa3, qb3;
        asm volatile(
            "global_load_dword %0,  %24, %41\n\t"
            "global_load_dword %1,  %25, %41\n\t"
            "global_load_dword %2,  %26, %41\n\t"
            "global_load_dword %3,  %27, %41\n\t"
            "global_load_dword %4,  %28, %41\n\t"
            "global_load_dword %5,  %29, %41\n\t"
            "global_load_dword %6,  %30, %41\n\t"
            "global_load_dword %7,  %31, %41\n\t"
            "global_load_dword %8,  %32, %41\n\t"
            "global_load_dword %9,  %33, %41\n\t"
            "global_load_dword %10, %34, %41\n\t"
            "global_load_dword %11, %35, %41\n\t"
            "global_load_dword %12, %36, %41\n\t"
            "global_load_dword %13, %37, %41\n\t"
            "global_load_dword %14, %38, %41\n\t"
            "global_load_dword %15, %39, %41\n\t"
            "global_load_dword %16, %40, %42\n\t"
            "global_load_dword %17, %40, %42 offset:4\n\t"
            "global_load_dword %18, %40, %42 offset:128\n\t"
            "global_load_dword %19, %40, %42 offset:132\n\t"
            "global_load_dword %20, %40, %42 offset:256\n\t"
            "global_load_dword %21, %40, %42 offset:260\n\t"
            "global_load_dword %22, %40, %42 offset:384\n\t"
            "global_load_dword %23, %40, %42 offset:388\n\t"
            "s_waitcnt vmcnt(0)"
            : "=&v"(v00), "=&v"(v01), "=&v"(v02), "=&v"(v03),
              "=&v"(v10), "=&v"(v11), "=&v"(v12), "=&v"(v13),
              "=&v"(v20), "=&v"(v21), "=&v"(v22), "=&v"(v23),
              "=&v"(v30), "=&v"(v31), "=&v"(v32), "=&v"(v33),
              "=&v"(qa0), "=&v"(qb0), "=&v"(qa1), "=&v"(qb1),
              "=&v"(qa2), "=&v"(qb2), "=&v"(qa3), "=&v"(qb3)
            : "v"(o00), "v"(o01), "v"(o02), "v"(o03),
              "v"(o10), "v"(o11), "v"(o12), "v"(o13),
              "v"(o20), "v"(o21), "v"(o22), "v"(o23),
              "v"(o30), "v"(o31), "v"(o32), "v"(o33),
              "v"(vq), "s"(p), "s"(q)
            : "memory");

        // ---- consume the two pairs of this batch ----
#pragma unroll
        for (int pp = 0; pp < 2; ++pp) {
            int na = nb + pp * 2, nbd = nb + pp * 2 + 1;
            int dgA = dgs[na], dgB = dgs[nbd];
            int nodeA = base_node + na, nodeB = base_node + nbd;

            float4 aA = {0.f,0.f,0.f,0.f}, aB = {0.f,0.f,0.f,0.f};
            if (pp == 0) {
                ACC(aA, v00) ACC(aA, v01) ACC(aA, v02) ACC(aA, v03)
                ACC(aB, v10) ACC(aB, v11) ACC(aB, v12) ACC(aB, v13)
            } else {
                ACC(aA, v20) ACC(aA, v21) ACC(aA, v22) ACC(aA, v23)
                ACC(aB, v30) ACC(aB, v31) ACC(aB, v32) ACC(aB, v33)
            }

            // --- deg in (16,32] tail: direct col32 slot loads (rare) ---
            if (dgA > 16) {
                for (int j = 16; j < 32 && j < dgA; j += 8) {
                    int r0 = j + g, r1 = j + 4 + g;     // <= 31 always
                    unsigned i0 = (r0 < dgA) ? ((unsigned)col32[(size_t)nodeA * 32 + r0] & 0x1FFFFu) : (unsigned)ZROW;
                    unsigned i1 = (r1 < dgA) ? ((unsigned)col32[(size_t)nodeA * 32 + r1] & 0x1FFFFu) : (unsigned)ZROW;
                    unsigned u0 = *(const unsigned*)(p + ((size_t)i0 << 6) + c * 4);
                    unsigned u1 = *(const unsigned*)(p + ((size_t)i1 << 6) + c * 4);
                    ACC(aA, u0) ACC(aA, u1)
                }
                if (dgA > 32) {                          // overflow fallback (~never)
                    int ovn = *ovf_cnt; if (ovn > OVF_CAP) ovn = OVF_CAP;
                    for (int k = 0; k < ovn; ++k) {
                        int2 e = ovf[k];
                        if (e.x == nodeA) {
                            unsigned i_ = (unsigned)e.y & 0x1FFFFu;
                            unsigned u = *(const unsigned*)(p + ((size_t)i_ << 6) + c * 4);
                            if (g == 0) ACC(aA, u)
                        }
                    }
                }
            }
            if (dgB > 16) {
                for (int j = 16; j < 32 && j < dgB; j += 8) {
                    int r0 = j + g, r1 = j + 4 + g;
                    unsigned i0 = (r0 < dgB) ? ((unsigned)col32[(size_t)nodeB * 32 + r0] & 0x1FFFFu) : (unsigned)ZROW;
                    unsigned i1 = (r1 < dgB) ? ((unsigned)col32[(size_t)nodeB * 32 + r1] & 0x1FFFFu) : (unsigned)ZROW;
                    unsigned u0 = *(const unsigned*)(p + ((size_t)i0 << 6) + c * 4);
                    unsigned u1 = *(const unsigned*)(p + ((size_t)i1 << 6) + c * 4);
                    ACC(aB, u0) ACC(aB, u1)
                }
                if (dgB > 32) {
                    int ovn = *ovf_cnt; if (ovn > OVF_CAP) ovn = OVF_CAP;
                    for (int k = 0; k < ovn; ++k) {
                        int2 e = ovf[k];
                        if (e.x == nodeB) {
                            unsigned i_ = (unsigned)e.y & 0x1FFFFu;
                            unsigned u = *(const unsigned*)(p + ((size_t)i_ << 6) + c * 4);
                            if (g == 0) ACC(aB, u)
                        }
                    }
                }
            }

            // --- cross-group reduce ---
            aA.x += __shfl_xor(aA.x, 16, 64); aA.y += __shfl_xor(aA.y, 16, 64);
            aA.z += __shfl_xor(aA.z, 16, 64); aA.w += __shfl_xor(aA.w, 16, 64);
            aB.x += __shfl_xor(aB.x, 16, 64); aB.y += __shfl_xor(aB.y, 16, 64);
            aB.z += __shfl_xor(aB.z, 16, 64); aB.w += __shfl_xor(aB.w, 16, 64);
            aA.x += __shfl_xor(aA.x, 32, 64); aA.y += __shfl_xor(aA.y, 32, 64);
            aA.z += __shfl_xor(aA.z, 32, 64); aA.w += __shfl_xor(aA.w, 32, 64);
            aB.x += __shfl_xor(aB.x, 32, 64); aB.y += __shfl_xor(aB.y, 32, 64);
            aB.z += __shfl_xor(aB.z, 32, 64); aB.w += __shfl_xor(aB.w, 32, 64);

            // --- epilogue for both nodes ---
#pragma unroll
            for (int e = 0; e < 2; ++e) {
                int node = base_node + nb + pp * 2 + e;
                int dg = (e == 0) ? dgA : dgB;
                float4 a = (e == 0) ? aA : aB;
                int li = pp * 2 + e;
                unsigned qlo = (li == 0) ? qa0 : (li == 1) ? qa1 : (li == 2) ? qa2 : qa3;
                unsigned qhi = (li == 0) ? qb0 : (li == 1) ? qb1 : (li == 2) ? qb2 : qb3;
                float inv = 1.0f / fmaxf((float)dg, 1.0f);
                float h0 = fmaxf(a.x * inv + b2v.x + bf2f_lo(qlo), 0.f);
                float h1 = fmaxf(a.y * inv + b2v.y + bf2f_hi(qlo), 0.f);
                float h2 = fmaxf(a.z * inv + b2v.z + bf2f_lo(qhi), 0.f);
                float h3 = fmaxf(a.w * inv + b2v.w + bf2f_hi(qhi), 0.f);

                float p0 = h0 * w01.x + h1 * w01.z + h2 * w23.x + h3 * w23.z;
                float p1 = h0 * w01.y + h1 * w01.w + h2 * w23.y + h3 * w23.w;
                if (g != 0) { p0 = 0.f; p1 = 0.f; }     // groups duplicate
                p0 += __shfl_down(p0, 8, 64);  p1 += __shfl_down(p1, 8, 64);
                p0 += __shfl_down(p0, 4, 64);  p1 += __shfl_down(p1, 4, 64);
                p0 += __shfl_down(p0, 2, 64);  p1 += __shfl_down(p1, 2, 64);
                p0 += __shfl_down(p0, 1, 64);  p1 += __shfl_down(p1, 1, 64);
                if (lane == 0) {
                    int grp = batch[node];
                    atomicAdd(&gsum[grp * 2 + 0], p0);
                    atomicAdd(&gsum[grp * 2 + 1], p1);
                }
            }
        }
    }
#undef ACC
}

// ---------------- finalize: out = gsum/cnt + bout ----------------
__global__ __launch_bounds__(256) void finalize_kernel(
    const float* __restrict__ gsum, const int* __restrict__ gstart,
    const float* __restrict__ bout, float* __restrict__ out)
{
    int g = blockIdx.x * 256 + threadIdx.x;
    if (g >= N_GRAPHS) return;
    int cnt = gstart[g + 1] - gstart[g];
    float inv = 1.0f / fmaxf((float)cnt, 1.0f);
    out[g * 2 + 0] = gsum[g * 2 + 0] * inv + bout[0];
    out[g * 2 + 1] = gsum[g * 2 + 1] * inv + bout[1];
}

extern "C" void kernel_launch(void* const* d_in, const int* in_sizes, int n_in,
                              void* d_out, int out_size, void* d_ws, size_t ws_size,
                              hipStream_t stream) {
    const int*   x    = (const int*)  d_in[0];
    const int*   ei   = (const int*)  d_in[1];
    const int*   batch= (const int*)  d_in[2];
    const float* emb  = (const float*)d_in[3];
    const float* W1l  = (const float*)d_in[4];
    const float* b1   = (const float*)d_in[5];
    const float* W1r  = (const float*)d_in[6];
    const float* W2l  = (const float*)d_in[7];
    const float* b2   = (const float*)d_in[8];
    const float* W2r  = (const float*)d_in[9];
    const float* Wout = (const float*)d_in[10];
    const float* bout = (const float*)d_in[11];
    float* out = (float*)d_out;

    const int* src = ei;
    const int* dst = ei + N_EDGES;

    char* ws = (char*)d_ws;
    size_t off = 0;
    unsigned char*  p8     = (unsigned char*) (ws + off); off += (size_t)(ZROW + 1) * 64;   // 8.39 MB (dummy row at ZROW)
    unsigned short* q16    = (unsigned short*)(ws + off); off += (size_t)N_NODES * 64 * 2;  // 12.8 MB
    unsigned short* w2frag = (unsigned short*)(ws + off); off += (size_t)8192 * 2;
    unsigned short* w1frag = (unsigned short*)(ws + off); off += (size_t)16384 * 2;         // 32 KB
    int*      col32  = (int*)     (ws + off); off += (size_t)NPAD * 32 * 4;                 // 12.8 MB (+pad)
    int2*     ovf    = (int2*)    (ws + off); off += (size_t)OVF_CAP * 8;                   // 512 KB
    int*      gstart = (int*)     (ws + off); off += (size_t)(N_GRAPHS + 2) * 4;
    // contiguous zero region: dcnt | ovf_cnt | gsum (one memset)
    int*      dcnt   = (int*)     (ws + off); off += (size_t)NPAD * 4;
    int*      ovfcnt = (int*)     (ws + off); off += (size_t)4;
    float*    gsum   = (float*)   (ws + off); off += (size_t)N_GRAPHS * 2 * 4;

    hipMemsetAsync(dcnt, 0, (size_t)NPAD * 4 + 4 + (size_t)N_GRAPHS * 2 * 4, stream);

    scatter_kernel<<<S_BLOCKS + GB + 32, 256, 0, stream>>>(
        src, dst, x, dcnt, col32, ovf, ovfcnt,
        batch, gstart, emb, W1l, W1r, W2l, W2r, w1frag, w2frag, p8);
    sage1_kernel<<<NB1, 256, 0, stream>>>(
        x, dcnt, col32, ovf, ovfcnt, w1frag, w2frag, b1, p8, q16);
    sage2_kernel<<<N_NODES / (4 * S2_NPW), 256, 0, stream>>>(
        p8, q16, dcnt, col32, ovf, ovfcnt, b2, Wout, batch, gsum);
    finalize_kernel<<<(N_GRAPHS + 255) / 256, 256, 0, stream>>>(gsum, gstart, bout, out);
}

// Round 11
// 195.290 us; speedup vs baseline: 1.1221x; 1.1221x over previous
//
#include <hip/hip_runtime.h>
#include <hip/hip_bf16.h>

#define N_NODES 100000
#define N_EDGES 1000000
#define EMB 64
#define HID 64
#define VOCAB 128
#define N_GRAPHS 2048

#define CBUCKET 256                                    // nodes per bucket
#define NBK ((N_NODES + CBUCKET - 1) / CBUCKET)        // 391
#define CAP 4096                                       // slots per bucket (E[cnt]=2560, 30 sigma)
#define CHUNK 2048                                     // halved: 489 blocks (2x parallelism)
#define SCAT_BLOCKS ((N_EDGES + CHUNK - 1) / CHUNK)    // 489
#define GB ((N_NODES + 255) / 256)                     // 391 gstart blocks
#define NPAD 100128                                    // node arrays padded to x128
#define OVF_CAP 65536
#define ZROW 0x1FFFF                                   // dummy row index in p8

#define BCASTF(v, l) __int_as_float(__builtin_amdgcn_readlane(__float_as_int(v), (l)))

typedef __attribute__((ext_vector_type(8))) short short8;
typedef __attribute__((ext_vector_type(4))) float f32x4;
typedef __attribute__((ext_vector_type(2))) float f32x2;

__device__ __forceinline__ float bf2f(unsigned short u) {
    return __uint_as_float((unsigned)u << 16);
}
__device__ __forceinline__ float bf2f_lo(unsigned u) {
    return __uint_as_float(u << 16);
}
__device__ __forceinline__ float bf2f_hi(unsigned u) {
    return __uint_as_float(u & 0xffff0000u);
}
__device__ __forceinline__ unsigned short f2bf(float f) {
    return __bfloat16_as_ushort(__float2bfloat16(f));
}

// ---- scatter: LDS-staged edge8 bucketizer (dense writes -- round-10 showed
//   direct random slotting costs 60 MB of write-allocate). CHUNK=2048 doubles
//   grid parallelism vs rounds 0-9. Blocks [489,880): gstart; [880,912):
//   precompute w1frag DIRECT (round-10-proven formula) + w2frag + dummy row.
__global__ __launch_bounds__(256) void scatter_kernel(
    const int* __restrict__ src, const int* __restrict__ dst,
    const int* __restrict__ x,
    int* __restrict__ cursor, unsigned* __restrict__ edge8,
    const int* __restrict__ batch, int* __restrict__ gstart,
    const float* __restrict__ emb, const float* __restrict__ W1l,
    const float* __restrict__ W1r,
    const float* __restrict__ W2l, const float* __restrict__ W2r,
    unsigned short* __restrict__ w1frag, unsigned short* __restrict__ w2frag,
    unsigned char* __restrict__ p8z)
{
    __shared__ unsigned earr[CHUNK];            // 8 KB packed payload
    __shared__ unsigned short karr[CHUNK];      // 4 KB bucket key (0..390)
    __shared__ int bcnt[NBK];
    __shared__ int bbase[NBK];
    int b = blockIdx.x;
    int t = threadIdx.x;

    if (b < SCAT_BLOCKS) {
        // 32-bit payload: src(17) | x[src](7, bits 17..23) | local_dst(8, bits 24..31)
        for (int i = t; i < NBK; i += 256) bcnt[i] = 0;
        __syncthreads();
        int e0 = b * CHUNK;
        int n = min(e0 + CHUNK, N_EDGES) - e0;
        for (int i = t; i < n; i += 256) {
            int d = dst[e0 + i];
            int s = src[e0 + i];
            int xv = x[s];                      // random 4B read, 400KB L2-hot
            int k = d >> 8;
            earr[i] = (unsigned)s | ((unsigned)xv << 17) | ((unsigned)(d & 255) << 24);
            karr[i] = (unsigned short)k;
            atomicAdd(&bcnt[k], 1);
        }
        __syncthreads();
        for (int i = t; i < NBK; i += 256) {
            int c = bcnt[i];
            bbase[i] = i * CAP + (c ? atomicAdd(&cursor[i], c) : 0);
            bcnt[i] = 0;                        // reuse as local cursor
        }
        __syncthreads();
        for (int i = t; i < n; i += 256) {
            int k = karr[i];
            int off = atomicAdd(&bcnt[k], 1);
            edge8[bbase[k] + off] = earr[i];    // dense single-writer runs
        }
    } else if (b < SCAT_BLOCKS + GB) {
        // ---- graph boundaries (batch sorted)
        int i = (b - SCAT_BLOCKS) * 256 + t;
        if (i >= N_NODES) return;
        int bg = batch[i];
        int bp = (i == 0) ? -1 : batch[i - 1];
        for (int g = bp + 1; g <= bg; ++g) gstart[g] = i;
        if (i == N_NODES - 1)
            for (int g = bg + 1; g <= N_GRAPHS; ++g) gstart[g] = N_NODES;
    } else {
        int vb = b - SCAT_BLOCKS - GB;           // 0..31
        // dummy row for sage2's branch-free gather (fp8 0x00 == +0.0)
        if (vb == 0 && t < 16)
            ((unsigned*)(p8z + (size_t)ZROW * 64))[t] = 0u;

        int wave = t >> 6, lane = t & 63;
        int v = vb * 4 + wave;                   // 0..127
        {
            float er = emb[v * 64 + lane];       // lane = d
            float al = 0.f, ar = 0.f;
#pragma unroll 8
            for (int d = 0; d < 64; ++d) {
                float e = BCASTF(er, d);
                al += e * W1l[d * 64 + lane];
                ar += e * W1r[d * 64 + lane];
            }
            // direct w1frag write (round-10-proven): kg=v / 128+v, n=lane
            int reml = (v >> 3) & 3, jj = v & 7;
            int ll = (reml << 4) | (lane & 15);
            int nt = lane >> 4;
            int gl = ((((v >> 5)) * 4 + nt) * 64 + ll) * 8 + jj;
            int gr = ((((v >> 5) + 4) * 4 + nt) * 64 + ll) * 8 + jj;
            w1frag[gl] = f2bf(al);
            w1frag[gr] = f2bf(ar);
        }
        // W2 B-fragment packing: g = tt*1024 + h*512 + l*8 + j
        int g = vb * 256 + t;
        int j = g & 7, l = (g >> 3) & 63, h = (g >> 9) & 1, tt = g >> 10;
        int k = h * 32 + ((l >> 4) * 8) + j;
        int n = tt * 16 + (l & 15);
        float w = (n < 64) ? W2l[k * 64 + n] : W2r[k * 64 + (n - 64)];
        w2frag[g] = f2bf(w);
    }
}

// ---- sage1: histogram-MFMA + MERGED CSR (csr_kernel deleted) ------------
//   One block per half-bucket (128 nodes). One pass over the bucket's edge8
//   run does: per-node slot counter (LDS), col32 staging (LDS, aliased with
//   msbuf), histogram packed-add. col32 then flushed DENSE to global (the
//   round-10 lesson: dense writes are ~free, random ones cost 60 MB), deg
//   written, then the proven hist-MFMA phases run unchanged.
__global__ __launch_bounds__(256) void sage1_kernel(
    const int* __restrict__ x,
    const unsigned* __restrict__ edge8, const int* __restrict__ cursor,
    int* __restrict__ dcnt, int* __restrict__ col32g,
    int2* __restrict__ ovf, int* __restrict__ ovf_cnt,
    const unsigned short* __restrict__ w1frag,
    const unsigned short* __restrict__ w2frag, const float* __restrict__ b1,
    unsigned char* __restrict__ p8, unsigned short* __restrict__ q16)
{
    __shared__ unsigned hist[128 * 32];                     // 16 KB, intact all phases
    __shared__ __align__(16) unsigned short msbuf[128 * 72];// 18 KB; aliases col32l
    __shared__ int cnt[128];
    __shared__ int xl[128];
    __shared__ float invd[128];
    int* col32l = (int*)msbuf;                              // 16 KB staging (phase 1)

    int blk = blockIdx.x, bucket = blk >> 1, half = blk & 1;
    int t = threadIdx.x;
    int nbase = bucket * CBUCKET + half * 128;

    for (int i = t * 4; i < 128 * 32; i += 1024)
        *(uint4*)&hist[i] = (uint4){0u, 0u, 0u, 0u};
    if (t < 128) {
        cnt[t] = 0;
        int node = nbase + t;
        xl[t] = (node < N_NODES) ? x[node] : 0;
    }
    __syncthreads();

    // ---- merged slotting + histogram over this bucket's edge run ----
    int lo = bucket * CAP, ecnt = cursor[bucket];
    for (int i = t; i < ecnt; i += 256) {
        unsigned e = edge8[lo + i];
        int ld = (int)(e >> 24);
        if ((ld >> 7) == half) {
            int r = ld & 127;
            int slot = atomicAdd(&cnt[r], 1);
            int pay = (int)(e & 0x1FFFF);
            if (slot < 32) {
                col32l[r * 32 + slot] = pay;
            } else {                            // deg>32: ~never (Poisson 10)
                int w = atomicAdd(ovf_cnt, 1);
                if (w < OVF_CAP) ovf[w] = make_int2(nbase + r, pay);
            }
            int xv = (int)((e >> 17) & 127);
            int wc = (xv >> 2) ^ ((r & 7) << 2);        // word swizzle
            atomicAdd(&hist[r * 32 + wc], 1u << ((xv & 3) * 8));
        }
    }
    __syncthreads();

    // ---- flush col32 (dense, coalesced) + deg; then LDS region is free ----
    {
        int4* dstp = (int4*)&col32g[(size_t)nbase * 32];
        const int4* srcp = (const int4*)col32l;
        for (int j = t; j < 1024; j += 256)     // 4096 ints = 1024 int4
            dstp[j] = srcp[j];
        if (t < 128) {
            dcnt[nbase + t] = cnt[t];
            invd[t] = 1.0f / fmaxf((float)cnt[t], 1.0f);
        }
    }
    __syncthreads();                            // col32l dead; msbuf live below

    int wave = t >> 6, lane = t & 63;
    int m = lane & 15;                  // A row / C col index
    int qd = lane >> 4;                 // k-subchunk / C row-group
    int hswz = (m & 7) << 2;            // row m's word swizzle

#pragma unroll
    for (int rt = wave * 2; rt < wave * 2 + 2; ++rt) {
        short8 acnt[4], aself[4];
#pragma unroll
        for (int kf = 0; kf < 4; ++kf) {
            int w0 = (kf * 8 + qd * 2) ^ hswz;
            uint2 u = *(const uint2*)&hist[(rt * 16 + m) * 32 + w0];
            short8 f;
            f[0] = (short)f2bf((float)(u.x & 255));
            f[1] = (short)f2bf((float)((u.x >> 8) & 255));
            f[2] = (short)f2bf((float)((u.x >> 16) & 255));
            f[3] = (short)f2bf((float)(u.x >> 24));
            f[4] = (short)f2bf((float)(u.y & 255));
            f[5] = (short)f2bf((float)((u.y >> 8) & 255));
            f[6] = (short)f2bf((float)((u.y >> 16) & 255));
            f[7] = (short)f2bf((float)(u.y >> 24));
            acnt[kf] = f;
        }
        int xv = xl[rt * 16 + m];
#pragma unroll
        for (int kf = 0; kf < 4; ++kf) {
            int v = xv - kf * 32 - qd * 8;
            short8 f;
#pragma unroll
            for (int j = 0; j < 8; ++j)
                f[j] = (v == j) ? (short)0x3F80 : (short)0;
            aself[kf] = f;
        }
        float iv0 = invd[rt * 16 + qd * 4 + 0];
        float iv1 = invd[rt * 16 + qd * 4 + 1];
        float iv2 = invd[rt * 16 + qd * 4 + 2];
        float iv3 = invd[rt * 16 + qd * 4 + 3];

#pragma unroll
        for (int nt = 0; nt < 4; ++nt) {
            f32x4 accA = {0.f, 0.f, 0.f, 0.f};
            f32x4 accS = {0.f, 0.f, 0.f, 0.f};
#pragma unroll
            for (int kf = 0; kf < 4; ++kf) {
                short8 bA = *(const short8*)(w1frag + ((kf * 4 + nt) * 64 + lane) * 8);
                accA = __builtin_amdgcn_mfma_f32_16x16x32_bf16(acnt[kf], bA, accA, 0, 0, 0);
            }
#pragma unroll
            for (int kf = 0; kf < 4; ++kf) {
                short8 bS = *(const short8*)(w1frag + (((kf + 4) * 4 + nt) * 64 + lane) * 8);
                accS = __builtin_amdgcn_mfma_f32_16x16x32_bf16(aself[kf], bS, accS, 0, 0, 0);
            }
            int c = nt * 16 + m;
            float b1c = b1[c];
            int rb = rt * 16 + qd * 4;
            msbuf[(rb + 0) * 72 + c] = f2bf(fmaxf(accA[0] * iv0 + accS[0] + b1c, 0.f));
            msbuf[(rb + 1) * 72 + c] = f2bf(fmaxf(accA[1] * iv1 + accS[1] + b1c, 0.f));
            msbuf[(rb + 2) * 72 + c] = f2bf(fmaxf(accA[2] * iv2 + accS[2] + b1c, 0.f));
            msbuf[(rb + 3) * 72 + c] = f2bf(fmaxf(accA[3] * iv3 + accS[3] + b1c, 0.f));
        }
    }
    __syncthreads();

#pragma unroll
    for (int rt = wave * 2; rt < wave * 2 + 2; ++rt) {
        const unsigned short* arow = &msbuf[(rt * 16 + m) * 72 + qd * 8];
        short8 a0 = *(const short8*)(arow);
        short8 a1 = *(const short8*)(arow + 32);
        int rowb = nbase + rt * 16 + qd * 4;

#pragma unroll
        for (int tt = 0; tt < 8; ++tt) {
            short8 b0 = *(const short8*)(w2frag + tt * 1024 + lane * 8);
            short8 b1v = *(const short8*)(w2frag + tt * 1024 + 512 + lane * 8);
            f32x4 acc = {0.f, 0.f, 0.f, 0.f};
            acc = __builtin_amdgcn_mfma_f32_16x16x32_bf16(a0, b0, acc, 0, 0, 0);
            acc = __builtin_amdgcn_mfma_f32_16x16x32_bf16(a1, b1v, acc, 0, 0, 0);
            int o = tt * 16 + m;
            if (o < 64) {
                int pk01 = __builtin_amdgcn_cvt_pk_fp8_f32(acc[0], acc[1], 0, false);
                int pk23 = __builtin_amdgcn_cvt_pk_fp8_f32(acc[2], acc[3], 0, false);
                if (rowb + 0 < N_NODES) p8[(rowb + 0) * 64 + o] = (unsigned char)(pk01 & 0xff);
                if (rowb + 1 < N_NODES) p8[(rowb + 1) * 64 + o] = (unsigned char)((pk01 >> 8) & 0xff);
                if (rowb + 2 < N_NODES) p8[(rowb + 2) * 64 + o] = (unsigned char)(pk23 & 0xff);
                if (rowb + 3 < N_NODES) p8[(rowb + 3) * 64 + o] = (unsigned char)((pk23 >> 8) & 0xff);
            } else {
                int oc = o & 63;
#pragma unroll
                for (int i = 0; i < 4; ++i)
                    if (rowb + i < N_NODES)
                        q16[(rowb + i) * 64 + oc] = f2bf(acc[i]);
            }
        }
    }
}

// ---- sage2: round-10 asm batched gather from col32 (proven passing).
//   Garbage slots (j>=deg) replaced by the dummy row; deg>32 -> overflow.
#define S2_NPW 8
__global__ __launch_bounds__(256) void sage2_kernel(
    const unsigned char* __restrict__ p, const unsigned short* __restrict__ q,
    const int* __restrict__ deg, const int* __restrict__ col32,
    const int2* __restrict__ ovf, const int* __restrict__ ovf_cnt,
    const float* __restrict__ b2,
    const float* __restrict__ Wout, const int* __restrict__ batch,
    float* __restrict__ gsum)
{
    int t = threadIdx.x;
    int wave = t >> 6, lane = t & 63;
    int base_node = (blockIdx.x * 4 + wave) * S2_NPW;   // exact cover
    int c = lane & 15;          // feature quad: features 4c..4c+3
    int g = lane >> 4;          // row group 0..3

    float4 b2v = ((const float4*)b2)[c];
    float4 w01 = ((const float4*)Wout)[c * 2];
    float4 w23 = ((const float4*)Wout)[c * 2 + 1];

    int dgs[S2_NPW];
#pragma unroll
    for (int n = 0; n < S2_NPW; ++n)
        dgs[n] = deg[base_node + n];

#define ACC(a, v) { f32x2 f01_ = __builtin_amdgcn_cvt_pk_f32_fp8((int)(v), false); \
                    f32x2 f23_ = __builtin_amdgcn_cvt_pk_f32_fp8((int)(v), true);  \
                    (a).x += f01_.x; (a).y += f01_.y; (a).z += f23_.x; (a).w += f23_.y; }

#pragma unroll
    for (int hb = 0; hb < 2; ++hb) {
        int nb = hb * 4;                        // nodes base_node+nb .. +nb+3

        // ---- asm block 1: 16 idx loads from col32, offset nn*128 + k*16 ----
        unsigned vc = (unsigned)((base_node + nb) * 128 + g * 4);
        unsigned i00, i01, i02, i03, i10, i11, i12, i13;
        unsigned i20, i21, i22, i23, i30, i31, i32, i33;
        asm volatile(
            "global_load_dword %0,  %16, %17\n\t"
            "global_load_dword %1,  %16, %17 offset:16\n\t"
            "global_load_dword %2,  %16, %17 offset:32\n\t"
            "global_load_dword %3,  %16, %17 offset:48\n\t"
            "global_load_dword %4,  %16, %17 offset:128\n\t"
            "global_load_dword %5,  %16, %17 offset:144\n\t"
            "global_load_dword %6,  %16, %17 offset:160\n\t"
            "global_load_dword %7,  %16, %17 offset:176\n\t"
            "global_load_dword %8,  %16, %17 offset:256\n\t"
            "global_load_dword %9,  %16, %17 offset:272\n\t"
            "global_load_dword %10, %16, %17 offset:288\n\t"
            "global_load_dword %11, %16, %17 offset:304\n\t"
            "global_load_dword %12, %16, %17 offset:384\n\t"
            "global_load_dword %13, %16, %17 offset:400\n\t"
            "global_load_dword %14, %16, %17 offset:416\n\t"
            "global_load_dword %15, %16, %17 offset:432\n\t"
            "s_waitcnt vmcnt(0)"
            : "=&v"(i00), "=&v"(i01), "=&v"(i02), "=&v"(i03),
              "=&v"(i10), "=&v"(i11), "=&v"(i12), "=&v"(i13),
              "=&v"(i20), "=&v"(i21), "=&v"(i22), "=&v"(i23),
              "=&v"(i30), "=&v"(i31), "=&v"(i32), "=&v"(i33)
            : "v"(vc), "s"(col32)
            : "memory");

        // ---- validity select (slot j = k*4+g vs deg) + x-bit mask ----
        unsigned cc4 = (unsigned)(c << 2);
        int d0 = dgs[nb + 0], d1 = dgs[nb + 1], d2 = dgs[nb + 2], d3 = dgs[nb + 3];
#define SEL(i_, dg_, k_) ((((k_) * 4 + g) < (dg_)) ? ((i_) & 0x1FFFFu) : (unsigned)ZROW)
        unsigned o00 = (SEL(i00, d0, 0) << 6) + cc4, o01 = (SEL(i01, d0, 1) << 6) + cc4;
        unsigned o02 = (SEL(i02, d0, 2) << 6) + cc4, o03 = (SEL(i03, d0, 3) << 6) + cc4;
        unsigned o10 = (SEL(i10, d1, 0) << 6) + cc4, o11 = (SEL(i11, d1, 1) << 6) + cc4;
        unsigned o12 = (SEL(i12, d1, 2) << 6) + cc4, o13 = (SEL(i13, d1, 3) << 6) + cc4;
        unsigned o20 = (SEL(i20, d2, 0) << 6) + cc4, o21 = (SEL(i21, d2, 1) << 6) + cc4;
        unsigned o22 = (SEL(i22, d2, 2) << 6) + cc4, o23 = (SEL(i23, d2, 3) << 6) + cc4;
        unsigned o30 = (SEL(i30, d3, 0) << 6) + cc4, o31 = (SEL(i31, d3, 1) << 6) + cc4;
        unsigned o32 = (SEL(i32, d3, 2) << 6) + cc4, o33 = (SEL(i33, d3, 3) << 6) + cc4;
#undef SEL
        unsigned vq = (unsigned)((base_node + nb) * 128 + c * 8);

        // ---- asm block 2: 16 p-gathers + 8 q-dwords, one waitcnt ----
        unsigned v00, v01, v02, v03, v10, v11, v12, v13;
        unsigned v20, v21, v22, v23, v30, v31, v32, v33;
        unsigned qa0, qb0, qa1, qb1, qa2, qb2, qa3, qb3;
        asm volatile(
            "global_load_dword %0,  %24, %41\n\t"
            "global_load_dword %1,  %25, %41\n\t"
            "global_load_dword %2,  %26, %41\n\t"
            "global_load_dword %3,  %27, %41\n\t"
            "global_load_dword %4,  %28, %41\n\t"
            "global_load_dword %5,  %29, %41\n\t"
            "global_load_dword %6,  %30, %41\n\t"
            "global_load_dword %7,  %31, %41\n\t"
            "global_load_dword %8,  %32, %41\n\t"
            "global_load_dword %9,  %33, %41\n\t"
            "global_load_dword %10, %34, %41\n\t"
            "global_load_dword %11, %35, %41\n\t"
            "global_load_dword %12, %36, %41\n\t"
            "global_load_dword %13, %37, %41\n\t"
            "global_load_dword %14, %38, %41\n\t"
            "global_load_dword %15, %39, %41\n\t"
            "global_load_dword %16, %40, %42\n\t"
            "global_load_dword %17, %40, %42 offset:4\n\t"
            "global_load_dword %18, %40, %42 offset:128\n\t"
            "global_load_dword %19, %40, %42 offset:132\n\t"
            "global_load_dword %20, %40, %42 offset:256\n\t"
            "global_load_dword %21, %40, %42 offset:260\n\t"
            "global_load_dword %22, %40, %42 offset:384\n\t"
            "global_load_dword %23, %40, %42 offset:388\n\t"
            "s_waitcnt vmcnt(0)"
            : "=&v"(v00), "=&v"(v01), "=&v"(v02), "=&v"(v03),
              "=&v"(v10), "=&v"(v11), "=&v"(v12), "=&v"(v13),
              "=&v"(v20), "=&v"(v21), "=&v"(v22), "=&v"(v23),
              "=&v"(v30), "=&v"(v31), "=&v"(v32), "=&v"(v33),
              "=&v"(qa0), "=&v"(qb0), "=&v"(qa1), "=&v"(qb1),
              "=&v"(qa2), "=&v"(qb2), "=&v"(qa3), "=&v"(qb3)
            : "v"(o00), "v"(o01), "v"(o02), "v"(o03),
              "v"(o10), "v"(o11), "v"(o12), "v"(o13),
              "v"(o20), "v"(o21), "v"(o22), "v"(o23),
              "v"(o30), "v"(o31), "v"(o32), "v"(o33),
              "v"(vq), "s"(p), "s"(q)
            : "memory");

        // ---- consume the two pairs of this batch ----
#pragma unroll
        for (int pp = 0; pp < 2; ++pp) {
            int na = nb + pp * 2, nbd = nb + pp * 2 + 1;
            int dgA = dgs[na], dgB = dgs[nbd];
            int nodeA = base_node + na, nodeB = base_node + nbd;

            float4 aA = {0.f,0.f,0.f,0.f}, aB = {0.f,0.f,0.f,0.f};
            if (pp == 0) {
                ACC(aA, v00) ACC(aA, v01) ACC(aA, v02) ACC(aA, v03)
                ACC(aB, v10) ACC(aB, v11) ACC(aB, v12) ACC(aB, v13)
            } else {
                ACC(aA, v20) ACC(aA, v21) ACC(aA, v22) ACC(aA, v23)
                ACC(aB, v30) ACC(aB, v31) ACC(aB, v32) ACC(aB, v33)
            }

            // --- deg in (16,32] tail: direct col32 slot loads (rare) ---
            if (dgA > 16) {
                for (int j = 16; j < 32 && j < dgA; j += 8) {
                    int r0 = j + g, r1 = j + 4 + g;     // <= 31 always
                    unsigned i0 = (r0 < dgA) ? ((unsigned)col32[(size_t)nodeA * 32 + r0] & 0x1FFFFu) : (unsigned)ZROW;
                    unsigned i1 = (r1 < dgA) ? ((unsigned)col32[(size_t)nodeA * 32 + r1] & 0x1FFFFu) : (unsigned)ZROW;
                    unsigned u0 = *(const unsigned*)(p + ((size_t)i0 << 6) + c * 4);
                    unsigned u1 = *(const unsigned*)(p + ((size_t)i1 << 6) + c * 4);
                    ACC(aA, u0) ACC(aA, u1)
                }
                if (dgA > 32) {                          // overflow fallback (~never)
                    int ovn = *ovf_cnt; if (ovn > OVF_CAP) ovn = OVF_CAP;
                    for (int k = 0; k < ovn; ++k) {
                        int2 e = ovf[k];
                        if (e.x == nodeA) {
                            unsigned i_ = (unsigned)e.y & 0x1FFFFu;
                            unsigned u = *(const unsigned*)(p + ((size_t)i_ << 6) + c * 4);
                            if (g == 0) ACC(aA, u)
                        }
                    }
                }
            }
            if (dgB > 16) {
                for (int j = 16; j < 32 && j < dgB; j += 8) {
                    int r0 = j + g, r1 = j + 4 + g;
                    unsigned i0 = (r0 < dgB) ? ((unsigned)col32[(size_t)nodeB * 32 + r0] & 0x1FFFFu) : (unsigned)ZROW;
                    unsigned i1 = (r1 < dgB) ? ((unsigned)col32[(size_t)nodeB * 32 + r1] & 0x1FFFFu) : (unsigned)ZROW;
                    unsigned u0 = *(const unsigned*)(p + ((size_t)i0 << 6) + c * 4);
                    unsigned u1 = *(const unsigned*)(p + ((size_t)i1 << 6) + c * 4);
                    ACC(aB, u0) ACC(aB, u1)
                }
                if (dgB > 32) {
                    int ovn = *ovf_cnt; if (ovn > OVF_CAP) ovn = OVF_CAP;
                    for (int k = 0; k < ovn; ++k) {
                        int2 e = ovf[k];
                        if (e.x == nodeB) {
                            unsigned i_ = (unsigned)e.y & 0x1FFFFu;
                            unsigned u = *(const unsigned*)(p + ((size_t)i_ << 6) + c * 4);
                            if (g == 0) ACC(aB, u)
                        }
                    }
                }
            }

            // --- cross-group reduce ---
            aA.x += __shfl_xor(aA.x, 16, 64); aA.y += __shfl_xor(aA.y, 16, 64);
            aA.z += __shfl_xor(aA.z, 16, 64); aA.w += __shfl_xor(aA.w, 16, 64);
            aB.x += __shfl_xor(aB.x, 16, 64); aB.y += __shfl_xor(aB.y, 16, 64);
            aB.z += __shfl_xor(aB.z, 16, 64); aB.w += __shfl_xor(aB.w, 16, 64);
            aA.x += __shfl_xor(aA.x, 32, 64); aA.y += __shfl_xor(aA.y, 32, 64);
            aA.z += __shfl_xor(aA.z, 32, 64); aA.w += __shfl_xor(aA.w, 32, 64);
            aB.x += __shfl_xor(aB.x, 32, 64); aB.y += __shfl_xor(aB.y, 32, 64);
            aB.z += __shfl_xor(aB.z, 32, 64); aB.w += __shfl_xor(aB.w, 32, 64);

            // --- epilogue for both nodes ---
#pragma unroll
            for (int e = 0; e < 2; ++e) {
                int node = base_node + nb + pp * 2 + e;
                int dg = (e == 0) ? dgA : dgB;
                float4 a = (e == 0) ? aA : aB;
                int li = pp * 2 + e;
                unsigned qlo = (li == 0) ? qa0 : (li == 1) ? qa1 : (li == 2) ? qa2 : qa3;
                unsigned qhi = (li == 0) ? qb0 : (li == 1) ? qb1 : (li == 2) ? qb2 : qb3;
                float inv = 1.0f / fmaxf((float)dg, 1.0f);
                float h0 = fmaxf(a.x * inv + b2v.x + bf2f_lo(qlo), 0.f);
                float h1 = fmaxf(a.y * inv + b2v.y + bf2f_hi(qlo), 0.f);
                float h2 = fmaxf(a.z * inv + b2v.z + bf2f_lo(qhi), 0.f);
                float h3 = fmaxf(a.w * inv + b2v.w + bf2f_hi(qhi), 0.f);

                float p0 = h0 * w01.x + h1 * w01.z + h2 * w23.x + h3 * w23.z;
                float p1 = h0 * w01.y + h1 * w01.w + h2 * w23.y + h3 * w23.w;
                if (g != 0) { p0 = 0.f; p1 = 0.f; }     // groups duplicate
                p0 += __shfl_down(p0, 8, 64);  p1 += __shfl_down(p1, 8, 64);
                p0 += __shfl_down(p0, 4, 64);  p1 += __shfl_down(p1, 4, 64);
                p0 += __shfl_down(p0, 2, 64);  p1 += __shfl_down(p1, 2, 64);
                p0 += __shfl_down(p0, 1, 64);  p1 += __shfl_down(p1, 1, 64);
                if (lane == 0) {
                    int grp = batch[node];
                    atomicAdd(&gsum[grp * 2 + 0], p0);
                    atomicAdd(&gsum[grp * 2 + 1], p1);
                }
            }
        }
    }
#undef ACC
}

// ---------------- finalize: out = gsum/cnt + bout ----------------
__global__ __launch_bounds__(256) void finalize_kernel(
    const float* __restrict__ gsum, const int* __restrict__ gstart,
    const float* __restrict__ bout, float* __restrict__ out)
{
    int g = blockIdx.x * 256 + threadIdx.x;
    if (g >= N_GRAPHS) return;
    int cnt = gstart[g + 1] - gstart[g];
    float inv = 1.0f / fmaxf((float)cnt, 1.0f);
    out[g * 2 + 0] = gsum[g * 2 + 0] * inv + bout[0];
    out[g * 2 + 1] = gsum[g * 2 + 1] * inv + bout[1];
}

extern "C" void kernel_launch(void* const* d_in, const int* in_sizes, int n_in,
                              void* d_out, int out_size, void* d_ws, size_t ws_size,
                              hipStream_t stream) {
    const int*   x    = (const int*)  d_in[0];
    const int*   ei   = (const int*)  d_in[1];
    const int*   batch= (const int*)  d_in[2];
    const float* emb  = (const float*)d_in[3];
    const float* W1l  = (const float*)d_in[4];
    const float* b1   = (const float*)d_in[5];
    const float* W1r  = (const float*)d_in[6];
    const float* W2l  = (const float*)d_in[7];
    const float* b2   = (const float*)d_in[8];
    const float* W2r  = (const float*)d_in[9];
    const float* Wout = (const float*)d_in[10];
    const float* bout = (const float*)d_in[11];
    float* out = (float*)d_out;

    const int* src = ei;
    const int* dst = ei + N_EDGES;

    char* ws = (char*)d_ws;
    size_t off = 0;
    unsigned char*  p8     = (unsigned char*) (ws + off); off += (size_t)(ZROW + 1) * 64;   // 8.39 MB (dummy row at ZROW)
    unsigned short* q16    = (unsigned short*)(ws + off); off += (size_t)N_NODES * 64 * 2;  // 12.8 MB
    unsigned short* w2frag = (unsigned short*)(ws + off); off += (size_t)8192 * 2;
    unsigned short* w1frag = (unsigned short*)(ws + off); off += (size_t)16384 * 2;         // 32 KB
    int*      col32  = (int*)     (ws + off); off += (size_t)NPAD * 32 * 4;                 // 12.8 MB
    int2*     ovf    = (int2*)    (ws + off); off += (size_t)OVF_CAP * 8;                   // 512 KB
    unsigned* edge8  = (unsigned*)(ws + off); off += (size_t)NBK * CAP * 4;                 // 6.4 MB
    int*      dcnt   = (int*)     (ws + off); off += (size_t)NPAD * 4;                      // written by sage1
    int*      gstart = (int*)     (ws + off); off += (size_t)(N_GRAPHS + 2) * 4;
    // contiguous zero region: cursor | ovf_cnt | gsum (one memset)
    int*      cursor = (int*)     (ws + off); off += (size_t)NBK * 4;
    int*      ovfcnt = (int*)     (ws + off); off += (size_t)4;
    float*    gsum   = (float*)   (ws + off); off += (size_t)N_GRAPHS * 2 * 4;

    hipMemsetAsync(cursor, 0, (size_t)NBK * 4 + 4 + (size_t)N_GRAPHS * 2 * 4, stream);

    scatter_kernel<<<SCAT_BLOCKS + GB + 32, 256, 0, stream>>>(
        src, dst, x, cursor, edge8,
        batch, gstart, emb, W1l, W1r, W2l, W2r, w1frag, w2frag, p8);
    sage1_kernel<<<NBK * 2, 256, 0, stream>>>(
        x, edge8, cursor, dcnt, col32, ovf, ovfcnt,
        w1frag, w2frag, b1, p8, q16);
    sage2_kernel<<<N_NODES / (4 * S2_NPW), 256, 0, stream>>>(
        p8, q16, dcnt, col32, ovf, ovfcnt, b2, Wout, batch, gsum);
    finalize_kernel<<<(N_GRAPHS + 255) / 256, 256, 0, stream>>>(gsum, gstart, bout, out);
}

// Round 12
// 182.813 us; speedup vs baseline: 1.1986x; 1.0682x over previous
//
#include <hip/hip_runtime.h>
#include <hip/hip_bf16.h>

#define N_NODES 100000
#define N_EDGES 1000000
#define EMB 64
#define HID 64
#define VOCAB 128
#define N_GRAPHS 2048

#define CBUCKET 256                                    // nodes per bucket
#define NBK ((N_NODES + CBUCKET - 1) / CBUCKET)        // 391
#define CAP 4096                                       // slots per bucket (E[cnt]=2560, 30 sigma)
#define CHUNK 4096                                     // proven rounds 0-9 (denser runs)
#define SCAT_BLOCKS ((N_EDGES + CHUNK - 1) / CHUNK)    // 245
#define GB ((N_NODES + 255) / 256)                     // 391 gstart blocks
#define NPAD 100128                                    // node arrays padded to x128
#define OVF_CAP 65536
#define ZROW 0x1FFFF                                   // dummy row index in p8

#define BCASTF(v, l) __int_as_float(__builtin_amdgcn_readlane(__float_as_int(v), (l)))

typedef __attribute__((ext_vector_type(8))) short short8;
typedef __attribute__((ext_vector_type(4))) float f32x4;
typedef __attribute__((ext_vector_type(2))) float f32x2;

__device__ __forceinline__ float bf2f(unsigned short u) {
    return __uint_as_float((unsigned)u << 16);
}
__device__ __forceinline__ float bf2f_lo(unsigned u) {
    return __uint_as_float(u << 16);
}
__device__ __forceinline__ float bf2f_hi(unsigned u) {
    return __uint_as_float(u & 0xffff0000u);
}
__device__ __forceinline__ unsigned short f2bf(float f) {
    return __bfloat16_as_ushort(__float2bfloat16(f));
}

// ---- scatter: LDS-staged edge8 bucketizer (CHUNK=4096, rounds-0-9 proven).
//   cursor is cacheline-strided (one line per bucket) to kill same-line
//   global-atomic serialization. Blocks [245,636): gstart; [636,668):
//   precompute w1frag DIRECT + w2frag + dummy row.
__global__ __launch_bounds__(256) void scatter_kernel(
    const int* __restrict__ src, const int* __restrict__ dst,
    const int* __restrict__ x,
    int* __restrict__ cursor, unsigned* __restrict__ edge8,
    const int* __restrict__ batch, int* __restrict__ gstart,
    const float* __restrict__ emb, const float* __restrict__ W1l,
    const float* __restrict__ W1r,
    const float* __restrict__ W2l, const float* __restrict__ W2r,
    unsigned short* __restrict__ w1frag, unsigned short* __restrict__ w2frag,
    unsigned char* __restrict__ p8z)
{
    __shared__ unsigned earr[CHUNK];            // 16 KB packed payload
    __shared__ unsigned short karr[CHUNK];      // 8 KB bucket key (0..390)
    __shared__ int bcnt[NBK];
    __shared__ int bbase[NBK];
    int b = blockIdx.x;
    int t = threadIdx.x;

    if (b < SCAT_BLOCKS) {
        // 32-bit payload: src(17) | x[src](7, bits 17..23) | local_dst(8, bits 24..31)
        for (int i = t; i < NBK; i += 256) bcnt[i] = 0;
        __syncthreads();
        int e0 = b * CHUNK;
        int n = min(e0 + CHUNK, N_EDGES) - e0;
        for (int i = t; i < n; i += 256) {
            int d = dst[e0 + i];
            int s = src[e0 + i];
            int xv = x[s];                      // random 4B read, 400KB L2-hot
            int k = d >> 8;
            earr[i] = (unsigned)s | ((unsigned)xv << 17) | ((unsigned)(d & 255) << 24);
            karr[i] = (unsigned short)k;
            atomicAdd(&bcnt[k], 1);
        }
        __syncthreads();
        for (int i = t; i < NBK; i += 256) {
            int c = bcnt[i];
            bbase[i] = i * CAP + (c ? atomicAdd(&cursor[i << 4], c) : 0);
            bcnt[i] = 0;                        // reuse as local cursor
        }
        __syncthreads();
        for (int i = t; i < n; i += 256) {
            int k = karr[i];
            int off = atomicAdd(&bcnt[k], 1);
            edge8[bbase[k] + off] = earr[i];    // dense single-writer runs
        }
    } else if (b < SCAT_BLOCKS + GB) {
        // ---- graph boundaries (batch sorted)
        int i = (b - SCAT_BLOCKS) * 256 + t;
        if (i >= N_NODES) return;
        int bg = batch[i];
        int bp = (i == 0) ? -1 : batch[i - 1];
        for (int g = bp + 1; g <= bg; ++g) gstart[g] = i;
        if (i == N_NODES - 1)
            for (int g = bg + 1; g <= N_GRAPHS; ++g) gstart[g] = N_NODES;
    } else {
        int vb = b - SCAT_BLOCKS - GB;           // 0..31
        // dummy row for sage2's branch-free gather (fp8 0x00 == +0.0)
        if (vb == 0 && t < 16)
            ((unsigned*)(p8z + (size_t)ZROW * 64))[t] = 0u;

        int wave = t >> 6, lane = t & 63;
        int v = vb * 4 + wave;                   // 0..127
        {
            float er = emb[v * 64 + lane];       // lane = d
            float al = 0.f, ar = 0.f;
#pragma unroll 8
            for (int d = 0; d < 64; ++d) {
                float e = BCASTF(er, d);
                al += e * W1l[d * 64 + lane];
                ar += e * W1r[d * 64 + lane];
            }
            // direct w1frag write (round-10-proven): kg=v / 128+v, n=lane
            int reml = (v >> 3) & 3, jj = v & 7;
            int ll = (reml << 4) | (lane & 15);
            int nt = lane >> 4;
            int gl = ((((v >> 5)) * 4 + nt) * 64 + ll) * 8 + jj;
            int gr = ((((v >> 5) + 4) * 4 + nt) * 64 + ll) * 8 + jj;
            w1frag[gl] = f2bf(al);
            w1frag[gr] = f2bf(ar);
        }
        // W2 B-fragment packing: g = tt*1024 + h*512 + l*8 + j
        int g = vb * 256 + t;
        int j = g & 7, l = (g >> 3) & 63, h = (g >> 9) & 1, tt = g >> 10;
        int k = h * 32 + ((l >> 4) * 8) + j;
        int n = tt * 16 + (l & 15);
        float w = (n < 64) ? W2l[k * 64 + n] : W2r[k * 64 + (n - 64)];
        w2frag[g] = f2bf(w);
    }
}

// ---- sage1: histogram-MFMA + merged CSR. col32l PRE-MASKED to ZROW so
//   sage2's gather needs no validity select (round-11's SEL cost 6 us).
__global__ __launch_bounds__(256) void sage1_kernel(
    const int* __restrict__ x,
    const unsigned* __restrict__ edge8, const int* __restrict__ cursor,
    int* __restrict__ dcnt, int* __restrict__ col32g,
    int2* __restrict__ ovf, int* __restrict__ ovf_cnt,
    const unsigned short* __restrict__ w1frag,
    const unsigned short* __restrict__ w2frag, const float* __restrict__ b1,
    unsigned char* __restrict__ p8, unsigned short* __restrict__ q16)
{
    __shared__ unsigned hist[128 * 32];                     // 16 KB, intact all phases
    __shared__ __align__(16) unsigned short msbuf[128 * 72];// 18 KB; aliases col32l
    __shared__ int cnt[128];
    __shared__ int xl[128];
    __shared__ float invd[128];
    int* col32l = (int*)msbuf;                              // 16 KB staging (phase 1)

    int blk = blockIdx.x, bucket = blk >> 1, half = blk & 1;
    int t = threadIdx.x;
    int nbase = bucket * CBUCKET + half * 128;

    for (int i = t * 4; i < 128 * 32; i += 1024) {
        *(uint4*)&hist[i] = (uint4){0u, 0u, 0u, 0u};
        *(int4*)&col32l[i] = (int4){ZROW, ZROW, ZROW, ZROW};    // pre-mask pads
    }
    if (t < 128) {
        cnt[t] = 0;
        int node = nbase + t;
        xl[t] = (node < N_NODES) ? x[node] : 0;
    }
    __syncthreads();

    // ---- merged slotting + histogram over this bucket's edge run ----
    int lo = bucket * CAP, ecnt = cursor[bucket << 4];
    for (int i = t; i < ecnt; i += 256) {
        unsigned e = edge8[lo + i];
        int ld = (int)(e >> 24);
        if ((ld >> 7) == half) {
            int r = ld & 127;
            int slot = atomicAdd(&cnt[r], 1);
            int pay = (int)(e & 0x1FFFF);
            if (slot < 32) {
                col32l[r * 32 + slot] = pay;
            } else {                            // deg>32: ~never (Poisson 10)
                int w = atomicAdd(ovf_cnt, 1);
                if (w < OVF_CAP) ovf[w] = make_int2(nbase + r, pay);
            }
            int xv = (int)((e >> 17) & 127);
            int wc = (xv >> 2) ^ ((r & 7) << 2);        // word swizzle
            atomicAdd(&hist[r * 32 + wc], 1u << ((xv & 3) * 8));
        }
    }
    __syncthreads();

    // ---- flush col32 (dense, coalesced) + deg; then LDS region is free ----
    {
        int4* dstp = (int4*)&col32g[(size_t)nbase * 32];
        const int4* srcp = (const int4*)col32l;
        for (int j = t; j < 1024; j += 256)     // 4096 ints = 1024 int4
            dstp[j] = srcp[j];
        if (t < 128) {
            dcnt[nbase + t] = cnt[t];
            invd[t] = 1.0f / fmaxf((float)cnt[t], 1.0f);
        }
    }
    __syncthreads();                            // col32l dead; msbuf live below

    int wave = t >> 6, lane = t & 63;
    int m = lane & 15;                  // A row / C col index
    int qd = lane >> 4;                 // k-subchunk / C row-group
    int hswz = (m & 7) << 2;            // row m's word swizzle

#pragma unroll
    for (int rt = wave * 2; rt < wave * 2 + 2; ++rt) {
        short8 acnt[4], aself[4];
#pragma unroll
        for (int kf = 0; kf < 4; ++kf) {
            int w0 = (kf * 8 + qd * 2) ^ hswz;
            uint2 u = *(const uint2*)&hist[(rt * 16 + m) * 32 + w0];
            short8 f;
            f[0] = (short)f2bf((float)(u.x & 255));
            f[1] = (short)f2bf((float)((u.x >> 8) & 255));
            f[2] = (short)f2bf((float)((u.x >> 16) & 255));
            f[3] = (short)f2bf((float)(u.x >> 24));
            f[4] = (short)f2bf((float)(u.y & 255));
            f[5] = (short)f2bf((float)((u.y >> 8) & 255));
            f[6] = (short)f2bf((float)((u.y >> 16) & 255));
            f[7] = (short)f2bf((float)(u.y >> 24));
            acnt[kf] = f;
        }
        int xv = xl[rt * 16 + m];
#pragma unroll
        for (int kf = 0; kf < 4; ++kf) {
            int v = xv - kf * 32 - qd * 8;
            short8 f;
#pragma unroll
            for (int j = 0; j < 8; ++j)
                f[j] = (v == j) ? (short)0x3F80 : (short)0;
            aself[kf] = f;
        }
        float iv0 = invd[rt * 16 + qd * 4 + 0];
        float iv1 = invd[rt * 16 + qd * 4 + 1];
        float iv2 = invd[rt * 16 + qd * 4 + 2];
        float iv3 = invd[rt * 16 + qd * 4 + 3];

#pragma unroll
        for (int nt = 0; nt < 4; ++nt) {
            f32x4 accA = {0.f, 0.f, 0.f, 0.f};
            f32x4 accS = {0.f, 0.f, 0.f, 0.f};
#pragma unroll
            for (int kf = 0; kf < 4; ++kf) {
                short8 bA = *(const short8*)(w1frag + ((kf * 4 + nt) * 64 + lane) * 8);
                accA = __builtin_amdgcn_mfma_f32_16x16x32_bf16(acnt[kf], bA, accA, 0, 0, 0);
            }
#pragma unroll
            for (int kf = 0; kf < 4; ++kf) {
                short8 bS = *(const short8*)(w1frag + (((kf + 4) * 4 + nt) * 64 + lane) * 8);
                accS = __builtin_amdgcn_mfma_f32_16x16x32_bf16(aself[kf], bS, accS, 0, 0, 0);
            }
            int c = nt * 16 + m;
            float b1c = b1[c];
            int rb = rt * 16 + qd * 4;
            msbuf[(rb + 0) * 72 + c] = f2bf(fmaxf(accA[0] * iv0 + accS[0] + b1c, 0.f));
            msbuf[(rb + 1) * 72 + c] = f2bf(fmaxf(accA[1] * iv1 + accS[1] + b1c, 0.f));
            msbuf[(rb + 2) * 72 + c] = f2bf(fmaxf(accA[2] * iv2 + accS[2] + b1c, 0.f));
            msbuf[(rb + 3) * 72 + c] = f2bf(fmaxf(accA[3] * iv3 + accS[3] + b1c, 0.f));
        }
    }
    __syncthreads();

#pragma unroll
    for (int rt = wave * 2; rt < wave * 2 + 2; ++rt) {
        const unsigned short* arow = &msbuf[(rt * 16 + m) * 72 + qd * 8];
        short8 a0 = *(const short8*)(arow);
        short8 a1 = *(const short8*)(arow + 32);
        int rowb = nbase + rt * 16 + qd * 4;

#pragma unroll
        for (int tt = 0; tt < 8; ++tt) {
            short8 b0 = *(const short8*)(w2frag + tt * 1024 + lane * 8);
            short8 b1v = *(const short8*)(w2frag + tt * 1024 + 512 + lane * 8);
            f32x4 acc = {0.f, 0.f, 0.f, 0.f};
            acc = __builtin_amdgcn_mfma_f32_16x16x32_bf16(a0, b0, acc, 0, 0, 0);
            acc = __builtin_amdgcn_mfma_f32_16x16x32_bf16(a1, b1v, acc, 0, 0, 0);
            int o = tt * 16 + m;
            if (o < 64) {
                int pk01 = __builtin_amdgcn_cvt_pk_fp8_f32(acc[0], acc[1], 0, false);
                int pk23 = __builtin_amdgcn_cvt_pk_fp8_f32(acc[2], acc[3], 0, false);
                if (rowb + 0 < N_NODES) p8[(rowb + 0) * 64 + o] = (unsigned char)(pk01 & 0xff);
                if (rowb + 1 < N_NODES) p8[(rowb + 1) * 64 + o] = (unsigned char)((pk01 >> 8) & 0xff);
                if (rowb + 2 < N_NODES) p8[(rowb + 2) * 64 + o] = (unsigned char)(pk23 & 0xff);
                if (rowb + 3 < N_NODES) p8[(rowb + 3) * 64 + o] = (unsigned char)((pk23 >> 8) & 0xff);
            } else {
                int oc = o & 63;
#pragma unroll
                for (int i = 0; i < 4; ++i)
                    if (rowb + i < N_NODES)
                        q16[(rowb + i) * 64 + oc] = f2bf(acc[i]);
            }
        }
    }
}

// ---- sage2: asm batched gather from PRE-MASKED col32 (round-9 form:
//   no SEL, no deg in the address path; pads point at the dummy row).
#define S2_NPW 8
__global__ __launch_bounds__(256) void sage2_kernel(
    const unsigned char* __restrict__ p, const unsigned short* __restrict__ q,
    const int* __restrict__ deg, const int* __restrict__ col32,
    const int2* __restrict__ ovf, const int* __restrict__ ovf_cnt,
    const float* __restrict__ b2,
    const float* __restrict__ Wout, const int* __restrict__ batch,
    float* __restrict__ gsum)
{
    int t = threadIdx.x;
    int wave = t >> 6, lane = t & 63;
    int base_node = (blockIdx.x * 4 + wave) * S2_NPW;   // exact cover
    int c = lane & 15;          // feature quad: features 4c..4c+3
    int g = lane >> 4;          // row group 0..3

    float4 b2v = ((const float4*)b2)[c];
    float4 w01 = ((const float4*)Wout)[c * 2];
    float4 w23 = ((const float4*)Wout)[c * 2 + 1];

    int dgs[S2_NPW];
#pragma unroll
    for (int n = 0; n < S2_NPW; ++n)
        dgs[n] = deg[base_node + n];

#define ACC(a, v) { f32x2 f01_ = __builtin_amdgcn_cvt_pk_f32_fp8((int)(v), false); \
                    f32x2 f23_ = __builtin_amdgcn_cvt_pk_f32_fp8((int)(v), true);  \
                    (a).x += f01_.x; (a).y += f01_.y; (a).z += f23_.x; (a).w += f23_.y; }

#pragma unroll
    for (int hb = 0; hb < 2; ++hb) {
        int nb = hb * 4;                        // nodes base_node+nb .. +nb+3

        // ---- asm block 1: 16 idx loads from col32, offset nn*128 + k*16 ----
        unsigned vc = (unsigned)((base_node + nb) * 128 + g * 4);
        unsigned i00, i01, i02, i03, i10, i11, i12, i13;
        unsigned i20, i21, i22, i23, i30, i31, i32, i33;
        asm volatile(
            "global_load_dword %0,  %16, %17\n\t"
            "global_load_dword %1,  %16, %17 offset:16\n\t"
            "global_load_dword %2,  %16, %17 offset:32\n\t"
            "global_load_dword %3,  %16, %17 offset:48\n\t"
            "global_load_dword %4,  %16, %17 offset:128\n\t"
            "global_load_dword %5,  %16, %17 offset:144\n\t"
            "global_load_dword %6,  %16, %17 offset:160\n\t"
            "global_load_dword %7,  %16, %17 offset:176\n\t"
            "global_load_dword %8,  %16, %17 offset:256\n\t"
            "global_load_dword %9,  %16, %17 offset:272\n\t"
            "global_load_dword %10, %16, %17 offset:288\n\t"
            "global_load_dword %11, %16, %17 offset:304\n\t"
            "global_load_dword %12, %16, %17 offset:384\n\t"
            "global_load_dword %13, %16, %17 offset:400\n\t"
            "global_load_dword %14, %16, %17 offset:416\n\t"
            "global_load_dword %15, %16, %17 offset:432\n\t"
            "s_waitcnt vmcnt(0)"
            : "=&v"(i00), "=&v"(i01), "=&v"(i02), "=&v"(i03),
              "=&v"(i10), "=&v"(i11), "=&v"(i12), "=&v"(i13),
              "=&v"(i20), "=&v"(i21), "=&v"(i22), "=&v"(i23),
              "=&v"(i30), "=&v"(i31), "=&v"(i32), "=&v"(i33)
            : "v"(vc), "s"(col32)
            : "memory");

        // ---- gather byte offsets: idx*64 + c*4 (idx pre-masked/padded) ----
        unsigned cc4 = (unsigned)(c << 2);
        unsigned o00 = (i00 << 6) + cc4, o01 = (i01 << 6) + cc4;
        unsigned o02 = (i02 << 6) + cc4, o03 = (i03 << 6) + cc4;
        unsigned o10 = (i10 << 6) + cc4, o11 = (i11 << 6) + cc4;
        unsigned o12 = (i12 << 6) + cc4, o13 = (i13 << 6) + cc4;
        unsigned o20 = (i20 << 6) + cc4, o21 = (i21 << 6) + cc4;
        unsigned o22 = (i22 << 6) + cc4, o23 = (i23 << 6) + cc4;
        unsigned o30 = (i30 << 6) + cc4, o31 = (i31 << 6) + cc4;
        unsigned o32 = (i32 << 6) + cc4, o33 = (i33 << 6) + cc4;
        unsigned vq = (unsigned)((base_node + nb) * 128 + c * 8);

        // ---- asm block 2: 16 p-gathers + 8 q-dwords, one waitcnt ----
        unsigned v00, v01, v02, v03, v10, v11, v12, v13;
        unsigned v20, v21, v22, v23, v30, v31, v32, v33;
        unsigned qa0, qb0, qa1, qb1, qa2, qb2, qa3, qb3;
        asm volatile(
            "global_load_dword %0,  %24, %41\n\t"
            "global_load_dword %1,  %25, %41\n\t"
            "global_load_dword %2,  %26, %41\n\t"
            "global_load_dword %3,  %27, %41\n\t"
            "global_load_dword %4,  %28, %41\n\t"
            "global_load_dword %5,  %29, %41\n\t"
            "global_load_dword %6,  %30, %41\n\t"
            "global_load_dword %7,  %31, %41\n\t"
            "global_load_dword %8,  %32, %41\n\t"
            "global_load_dword %9,  %33, %41\n\t"
            "global_load_dword %10, %34, %41\n\t"
            "global_load_dword %11, %35, %41\n\t"
            "global_load_dword %12, %36, %41\n\t"
            "global_load_dword %13, %37, %41\n\t"
            "global_load_dword %14, %38, %41\n\t"
            "global_load_dword %15, %39, %41\n\t"
            "global_load_dword %16, %40, %42\n\t"
            "global_load_dword %17, %40, %42 offset:4\n\t"
            "global_load_dword %18, %40, %42 offset:128\n\t"
            "global_load_dword %19, %40, %42 offset:132\n\t"
            "global_load_dword %20, %40, %42 offset:256\n\t"
            "global_load_dword %21, %40, %42 offset:260\n\t"
            "global_load_dword %22, %40, %42 offset:384\n\t"
            "global_load_dword %23, %40, %42 offset:388\n\t"
            "s_waitcnt vmcnt(0)"
            : "=&v"(v00), "=&v"(v01), "=&v"(v02), "=&v"(v03),
              "=&v"(v10), "=&v"(v11), "=&v"(v12), "=&v"(v13),
              "=&v"(v20), "=&v"(v21), "=&v"(v22), "=&v"(v23),
              "=&v"(v30), "=&v"(v31), "=&v"(v32), "=&v"(v33),
              "=&v"(qa0), "=&v"(qb0), "=&v"(qa1), "=&v"(qb1),
              "=&v"(qa2), "=&v"(qb2), "=&v"(qa3), "=&v"(qb3)
            : "v"(o00), "v"(o01), "v"(o02), "v"(o03),
              "v"(o10), "v"(o11), "v"(o12), "v"(o13),
              "v"(o20), "v"(o21), "v"(o22), "v"(o23),
              "v"(o30), "v"(o31), "v"(o32), "v"(o33),
              "v"(vq), "s"(p), "s"(q)
            : "memory");

        // ---- consume the two pairs of this batch ----
#pragma unroll
        for (int pp = 0; pp < 2; ++pp) {
            int na = nb + pp * 2, nbd = nb + pp * 2 + 1;
            int dgA = dgs[na], dgB = dgs[nbd];
            int nodeA = base_node + na, nodeB = base_node + nbd;

            float4 aA = {0.f,0.f,0.f,0.f}, aB = {0.f,0.f,0.f,0.f};
            if (pp == 0) {
                ACC(aA, v00) ACC(aA, v01) ACC(aA, v02) ACC(aA, v03)
                ACC(aB, v10) ACC(aB, v11) ACC(aB, v12) ACC(aB, v13)
            } else {
                ACC(aA, v20) ACC(aA, v21) ACC(aA, v22) ACC(aA, v23)
                ACC(aB, v30) ACC(aB, v31) ACC(aB, v32) ACC(aB, v33)
            }

            // --- deg>16 tail: direct col32 slot loads (pre-masked, rare) ---
            if (dgA > 16) {
                for (int j = 16; j < 32; j += 8) {
                    unsigned i0 = (unsigned)col32[(size_t)nodeA * 32 + j + g];
                    unsigned i1 = (unsigned)col32[(size_t)nodeA * 32 + j + 4 + g];
                    unsigned u0 = *(const unsigned*)(p + ((size_t)i0 << 6) + c * 4);
                    unsigned u1 = *(const unsigned*)(p + ((size_t)i1 << 6) + c * 4);
                    ACC(aA, u0) ACC(aA, u1)
                }
                if (dgA > 32) {                          // overflow fallback (~never)
                    int ovn = *ovf_cnt; if (ovn > OVF_CAP) ovn = OVF_CAP;
                    for (int k = 0; k < ovn; ++k) {
                        int2 e = ovf[k];
                        if (e.x == nodeA) {
                            unsigned i_ = (unsigned)e.y & 0x1FFFFu;
                            unsigned u = *(const unsigned*)(p + ((size_t)i_ << 6) + c * 4);
                            if (g == 0) ACC(aA, u)
                        }
                    }
                }
            }
            if (dgB > 16) {
                for (int j = 16; j < 32; j += 8) {
                    unsigned i0 = (unsigned)col32[(size_t)nodeB * 32 + j + g];
                    unsigned i1 = (unsigned)col32[(size_t)nodeB * 32 + j + 4 + g];
                    unsigned u0 = *(const unsigned*)(p + ((size_t)i0 << 6) + c * 4);
                    unsigned u1 = *(const unsigned*)(p + ((size_t)i1 << 6) + c * 4);
                    ACC(aB, u0) ACC(aB, u1)
                }
                if (dgB > 32) {
                    int ovn = *ovf_cnt; if (ovn > OVF_CAP) ovn = OVF_CAP;
                    for (int k = 0; k < ovn; ++k) {
                        int2 e = ovf[k];
                        if (e.x == nodeB) {
                            unsigned i_ = (unsigned)e.y & 0x1FFFFu;
                            unsigned u = *(const unsigned*)(p + ((size_t)i_ << 6) + c * 4);
                            if (g == 0) ACC(aB, u)
                        }
                    }
                }
            }

            // --- cross-group reduce ---
            aA.x += __shfl_xor(aA.x, 16, 64); aA.y += __shfl_xor(aA.y, 16, 64);
            aA.z += __shfl_xor(aA.z, 16, 64); aA.w += __shfl_xor(aA.w, 16, 64);
            aB.x += __shfl_xor(aB.x, 16, 64); aB.y += __shfl_xor(aB.y, 16, 64);
            aB.z += __shfl_xor(aB.z, 16, 64); aB.w += __shfl_xor(aB.w, 16, 64);
            aA.x += __shfl_xor(aA.x, 32, 64); aA.y += __shfl_xor(aA.y, 32, 64);
            aA.z += __shfl_xor(aA.z, 32, 64); aA.w += __shfl_xor(aA.w, 32, 64);
            aB.x += __shfl_xor(aB.x, 32, 64); aB.y += __shfl_xor(aB.y, 32, 64);
            aB.z += __shfl_xor(aB.z, 32, 64); aB.w += __shfl_xor(aB.w, 32, 64);

            // --- epilogue for both nodes ---
#pragma unroll
            for (int e = 0; e < 2; ++e) {
                int node = base_node + nb + pp * 2 + e;
                int dg = (e == 0) ? dgA : dgB;
                float4 a = (e == 0) ? aA : aB;
                int li = pp * 2 + e;
                unsigned qlo = (li == 0) ? qa0 : (li == 1) ? qa1 : (li == 2) ? qa2 : qa3;
                unsigned qhi = (li == 0) ? qb0 : (li == 1) ? qb1 : (li == 2) ? qb2 : qb3;
                float inv = 1.0f / fmaxf((float)dg, 1.0f);
                float h0 = fmaxf(a.x * inv + b2v.x + bf2f_lo(qlo), 0.f);
                float h1 = fmaxf(a.y * inv + b2v.y + bf2f_hi(qlo), 0.f);
                float h2 = fmaxf(a.z * inv + b2v.z + bf2f_lo(qhi), 0.f);
                float h3 = fmaxf(a.w * inv + b2v.w + bf2f_hi(qhi), 0.f);

                float p0 = h0 * w01.x + h1 * w01.z + h2 * w23.x + h3 * w23.z;
                float p1 = h0 * w01.y + h1 * w01.w + h2 * w23.y + h3 * w23.w;
                if (g != 0) { p0 = 0.f; p1 = 0.f; }     // groups duplicate
                p0 += __shfl_down(p0, 8, 64);  p1 += __shfl_down(p1, 8, 64);
                p0 += __shfl_down(p0, 4, 64);  p1 += __shfl_down(p1, 4, 64);
                p0 += __shfl_down(p0, 2, 64);  p1 += __shfl_down(p1, 2, 64);
                p0 += __shfl_down(p0, 1, 64);  p1 += __shfl_down(p1, 1, 64);
                if (lane == 0) {
                    int grp = batch[node];
                    atomicAdd(&gsum[grp * 2 + 0], p0);
                    atomicAdd(&gsum[grp * 2 + 1], p1);
                }
            }
        }
    }
#undef ACC
}

// ---------------- finalize: out = gsum/cnt + bout ----------------
__global__ __launch_bounds__(256) void finalize_kernel(
    const float* __restrict__ gsum, const int* __restrict__ gstart,
    const float* __restrict__ bout, float* __restrict__ out)
{
    int g = blockIdx.x * 256 + threadIdx.x;
    if (g >= N_GRAPHS) return;
    int cnt = gstart[g + 1] - gstart[g];
    float inv = 1.0f / fmaxf((float)cnt, 1.0f);
    out[g * 2 + 0] = gsum[g * 2 + 0] * inv + bout[0];
    out[g * 2 + 1] = gsum[g * 2 + 1] * inv + bout[1];
}

extern "C" void kernel_launch(void* const* d_in, const int* in_sizes, int n_in,
                              void* d_out, int out_size, void* d_ws, size_t ws_size,
                              hipStream_t stream) {
    const int*   x    = (const int*)  d_in[0];
    const int*   ei   = (const int*)  d_in[1];
    const int*   batch= (const int*)  d_in[2];
    const float* emb  = (const float*)d_in[3];
    const float* W1l  = (const float*)d_in[4];
    const float* b1   = (const float*)d_in[5];
    const float* W1r  = (const float*)d_in[6];
    const float* W2l  = (const float*)d_in[7];
    const float* b2   = (const float*)d_in[8];
    const float* W2r  = (const float*)d_in[9];
    const float* Wout = (const float*)d_in[10];
    const float* bout = (const float*)d_in[11];
    float* out = (float*)d_out;

    const int* src = ei;
    const int* dst = ei + N_EDGES;

    char* ws = (char*)d_ws;
    size_t off = 0;
    unsigned char*  p8     = (unsigned char*) (ws + off); off += (size_t)(ZROW + 1) * 64;   // 8.39 MB (dummy row at ZROW)
    unsigned short* q16    = (unsigned short*)(ws + off); off += (size_t)N_NODES * 64 * 2;  // 12.8 MB
    unsigned short* w2frag = (unsigned short*)(ws + off); off += (size_t)8192 * 2;
    unsigned short* w1frag = (unsigned short*)(ws + off); off += (size_t)16384 * 2;         // 32 KB
    int*      col32  = (int*)     (ws + off); off += (size_t)NPAD * 32 * 4;                 // 12.8 MB
    int2*     ovf    = (int2*)    (ws + off); off += (size_t)OVF_CAP * 8;                   // 512 KB
    unsigned* edge8  = (unsigned*)(ws + off); off += (size_t)NBK * CAP * 4;                 // 6.4 MB
    int*      dcnt   = (int*)     (ws + off); off += (size_t)NPAD * 4;                      // written by sage1
    int*      gstart = (int*)     (ws + off); off += (size_t)(N_GRAPHS + 2) * 4;
    // contiguous zero region: cursor (strided x16) | ovf_cnt | gsum (one memset)
    int*      cursor = (int*)     (ws + off); off += (size_t)NBK * 16 * 4;                  // 25 KB
    int*      ovfcnt = (int*)     (ws + off); off += (size_t)4;
    float*    gsum   = (float*)   (ws + off); off += (size_t)N_GRAPHS * 2 * 4;

    hipMemsetAsync(cursor, 0, (size_t)NBK * 16 * 4 + 4 + (size_t)N_GRAPHS * 2 * 4, stream);

    scatter_kernel<<<SCAT_BLOCKS + GB + 32, 256, 0, stream>>>(
        src, dst, x, cursor, edge8,
        batch, gstart, emb, W1l, W1r, W2l, W2r, w1frag, w2frag, p8);
    sage1_kernel<<<NBK * 2, 256, 0, stream>>>(
        x, edge8, cursor, dcnt, col32, ovf, ovfcnt,
        w1frag, w2frag, b1, p8, q16);
    sage2_kernel<<<N_NODES / (4 * S2_NPW), 256, 0, stream>>>(
        p8, q16, dcnt, col32, ovf, ovfcnt, b2, Wout, batch, gsum);
    finalize_kernel<<<(N_GRAPHS + 255) / 256, 256, 0, stream>>>(gsum, gstart, bout, out);
}

// Round 13
// 182.284 us; speedup vs baseline: 1.2021x; 1.0029x over previous
//
#include <hip/hip_runtime.h>
#include <hip/hip_bf16.h>

#define N_NODES 100000
#define N_EDGES 1000000
#define EMB 64
#define HID 64
#define VOCAB 128
#define N_GRAPHS 2048

#define CBUCKET 256                                    // nodes per bucket
#define NBK ((N_NODES + CBUCKET - 1) / CBUCKET)        // 391
#define CAP 4096                                       // slots per bucket (E[cnt]=2560, 30 sigma)
#define CHUNK 4096                                     // proven rounds 0-9/12 (dense runs)
#define SCAT_BLOCKS ((N_EDGES + CHUNK - 1) / CHUNK)    // 245
#define GB ((N_NODES + 255) / 256)                     // 391 gstart blocks
#define NPAD 100128                                    // node arrays padded to x128
#define OVF_CAP 65536
#define ZROW 0x1FFFF                                   // dummy row index in p8

#define BCASTF(v, l) __int_as_float(__builtin_amdgcn_readlane(__float_as_int(v), (l)))

typedef __attribute__((ext_vector_type(8))) short short8;
typedef __attribute__((ext_vector_type(4))) float f32x4;
typedef __attribute__((ext_vector_type(2))) float f32x2;

__device__ __forceinline__ float bf2f(unsigned short u) {
    return __uint_as_float((unsigned)u << 16);
}
__device__ __forceinline__ float bf2f_lo(unsigned u) {
    return __uint_as_float(u << 16);
}
__device__ __forceinline__ float bf2f_hi(unsigned u) {
    return __uint_as_float(u & 0xffff0000u);
}
__device__ __forceinline__ unsigned short f2bf(float f) {
    return __bfloat16_as_ushort(__float2bfloat16(f));
}

// ---- scatter: LDS-staged edge8 bucketizer, NOW 1024 THREADS on the edge
//   blocks: 16 waves/CU (was 4) hides the random x[s] L2 gather latency;
//   per-pass serial depth 16 -> 4. Algorithm and write pattern unchanged
//   (round-12 proven). gstart/precompute branches guard to t<256 and stay
//   merged so they still overlap the edge phase.
__global__ __launch_bounds__(1024) void scatter_kernel(
    const int* __restrict__ src, const int* __restrict__ dst,
    const int* __restrict__ x,
    int* __restrict__ cursor, unsigned* __restrict__ edge8,
    const int* __restrict__ batch, int* __restrict__ gstart,
    const float* __restrict__ emb, const float* __restrict__ W1l,
    const float* __restrict__ W1r,
    const float* __restrict__ W2l, const float* __restrict__ W2r,
    unsigned short* __restrict__ w1frag, unsigned short* __restrict__ w2frag,
    unsigned char* __restrict__ p8z)
{
    __shared__ unsigned earr[CHUNK];            // 16 KB packed payload
    __shared__ unsigned short karr[CHUNK];      // 8 KB bucket key (0..390)
    __shared__ int bcnt[NBK];
    __shared__ int bbase[NBK];
    int b = blockIdx.x;
    int t = threadIdx.x;

    if (b < SCAT_BLOCKS) {
        // 32-bit payload: src(17) | x[src](7, bits 17..23) | local_dst(8, bits 24..31)
        for (int i = t; i < NBK; i += 1024) bcnt[i] = 0;
        __syncthreads();
        int e0 = b * CHUNK;
        int n = min(e0 + CHUNK, N_EDGES) - e0;
        for (int i = t; i < n; i += 1024) {
            int d = dst[e0 + i];
            int s = src[e0 + i];
            int xv = x[s];                      // random 4B read, 400KB L2-hot
            int k = d >> 8;
            earr[i] = (unsigned)s | ((unsigned)xv << 17) | ((unsigned)(d & 255) << 24);
            karr[i] = (unsigned short)k;
            atomicAdd(&bcnt[k], 1);
        }
        __syncthreads();
        for (int i = t; i < NBK; i += 1024) {
            int c = bcnt[i];
            bbase[i] = i * CAP + (c ? atomicAdd(&cursor[i << 4], c) : 0);
            bcnt[i] = 0;                        // reuse as local cursor
        }
        __syncthreads();
        for (int i = t; i < n; i += 1024) {
            int k = karr[i];
            int off = atomicAdd(&bcnt[k], 1);
            edge8[bbase[k] + off] = earr[i];    // dense single-writer runs
        }
    } else if (b < SCAT_BLOCKS + GB) {
        if (t >= 256) return;                   // 256-thread logic
        // ---- graph boundaries (batch sorted)
        int i = (b - SCAT_BLOCKS) * 256 + t;
        if (i >= N_NODES) return;
        int bg = batch[i];
        int bp = (i == 0) ? -1 : batch[i - 1];
        for (int g = bp + 1; g <= bg; ++g) gstart[g] = i;
        if (i == N_NODES - 1)
            for (int g = bg + 1; g <= N_GRAPHS; ++g) gstart[g] = N_NODES;
    } else {
        if (t >= 256) return;                   // 256-thread logic
        int vb = b - SCAT_BLOCKS - GB;           // 0..31
        // dummy row for sage2's branch-free gather (fp8 0x00 == +0.0)
        if (vb == 0 && t < 16)
            ((unsigned*)(p8z + (size_t)ZROW * 64))[t] = 0u;

        int wave = t >> 6, lane = t & 63;
        int v = vb * 4 + wave;                   // 0..127
        {
            float er = emb[v * 64 + lane];       // lane = d
            float al = 0.f, ar = 0.f;
#pragma unroll 8
            for (int d = 0; d < 64; ++d) {
                float e = BCASTF(er, d);
                al += e * W1l[d * 64 + lane];
                ar += e * W1r[d * 64 + lane];
            }
            // direct w1frag write (round-10-proven): kg=v / 128+v, n=lane
            int reml = (v >> 3) & 3, jj = v & 7;
            int ll = (reml << 4) | (lane & 15);
            int nt = lane >> 4;
            int gl = ((((v >> 5)) * 4 + nt) * 64 + ll) * 8 + jj;
            int gr = ((((v >> 5) + 4) * 4 + nt) * 64 + ll) * 8 + jj;
            w1frag[gl] = f2bf(al);
            w1frag[gr] = f2bf(ar);
        }
        // W2 B-fragment packing: g = tt*1024 + h*512 + l*8 + j
        int g = vb * 256 + t;
        int j = g & 7, l = (g >> 3) & 63, h = (g >> 9) & 1, tt = g >> 10;
        int k = h * 32 + ((l >> 4) * 8) + j;
        int n = tt * 16 + (l & 15);
        float w = (n < 64) ? W2l[k * 64 + n] : W2r[k * 64 + (n - 64)];
        w2frag[g] = f2bf(w);
    }
}

// ---- sage1: histogram-MFMA + merged CSR (round-12 proven, unchanged).
//   col32l PRE-MASKED to ZROW so sage2's gather needs no validity select.
__global__ __launch_bounds__(256) void sage1_kernel(
    const int* __restrict__ x,
    const unsigned* __restrict__ edge8, const int* __restrict__ cursor,
    int* __restrict__ dcnt, int* __restrict__ col32g,
    int2* __restrict__ ovf, int* __restrict__ ovf_cnt,
    const unsigned short* __restrict__ w1frag,
    const unsigned short* __restrict__ w2frag, const float* __restrict__ b1,
    unsigned char* __restrict__ p8, unsigned short* __restrict__ q16)
{
    __shared__ unsigned hist[128 * 32];                     // 16 KB, intact all phases
    __shared__ __align__(16) unsigned short msbuf[128 * 72];// 18 KB; aliases col32l
    __shared__ int cnt[128];
    __shared__ int xl[128];
    __shared__ float invd[128];
    int* col32l = (int*)msbuf;                              // 16 KB staging (phase 1)

    int blk = blockIdx.x, bucket = blk >> 1, half = blk & 1;
    int t = threadIdx.x;
    int nbase = bucket * CBUCKET + half * 128;

    for (int i = t * 4; i < 128 * 32; i += 1024) {
        *(uint4*)&hist[i] = (uint4){0u, 0u, 0u, 0u};
        *(int4*)&col32l[i] = (int4){ZROW, ZROW, ZROW, ZROW};    // pre-mask pads
    }
    if (t < 128) {
        cnt[t] = 0;
        int node = nbase + t;
        xl[t] = (node < N_NODES) ? x[node] : 0;
    }
    __syncthreads();

    // ---- merged slotting + histogram over this bucket's edge run ----
    int lo = bucket * CAP, ecnt = cursor[bucket << 4];
    for (int i = t; i < ecnt; i += 256) {
        unsigned e = edge8[lo + i];
        int ld = (int)(e >> 24);
        if ((ld >> 7) == half) {
            int r = ld & 127;
            int slot = atomicAdd(&cnt[r], 1);
            int pay = (int)(e & 0x1FFFF);
            if (slot < 32) {
                col32l[r * 32 + slot] = pay;
            } else {                            // deg>32: ~never (Poisson 10)
                int w = atomicAdd(ovf_cnt, 1);
                if (w < OVF_CAP) ovf[w] = make_int2(nbase + r, pay);
            }
            int xv = (int)((e >> 17) & 127);
            int wc = (xv >> 2) ^ ((r & 7) << 2);        // word swizzle
            atomicAdd(&hist[r * 32 + wc], 1u << ((xv & 3) * 8));
        }
    }
    __syncthreads();

    // ---- flush col32 (dense, coalesced) + deg; then LDS region is free ----
    {
        int4* dstp = (int4*)&col32g[(size_t)nbase * 32];
        const int4* srcp = (const int4*)col32l;
        for (int j = t; j < 1024; j += 256)     // 4096 ints = 1024 int4
            dstp[j] = srcp[j];
        if (t < 128) {
            dcnt[nbase + t] = cnt[t];
            invd[t] = 1.0f / fmaxf((float)cnt[t], 1.0f);
        }
    }
    __syncthreads();                            // col32l dead; msbuf live below

    int wave = t >> 6, lane = t & 63;
    int m = lane & 15;                  // A row / C col index
    int qd = lane >> 4;                 // k-subchunk / C row-group
    int hswz = (m & 7) << 2;            // row m's word swizzle

#pragma unroll
    for (int rt = wave * 2; rt < wave * 2 + 2; ++rt) {
        short8 acnt[4], aself[4];
#pragma unroll
        for (int kf = 0; kf < 4; ++kf) {
            int w0 = (kf * 8 + qd * 2) ^ hswz;
            uint2 u = *(const uint2*)&hist[(rt * 16 + m) * 32 + w0];
            short8 f;
            f[0] = (short)f2bf((float)(u.x & 255));
            f[1] = (short)f2bf((float)((u.x >> 8) & 255));
            f[2] = (short)f2bf((float)((u.x >> 16) & 255));
            f[3] = (short)f2bf((float)(u.x >> 24));
            f[4] = (short)f2bf((float)(u.y & 255));
            f[5] = (short)f2bf((float)((u.y >> 8) & 255));
            f[6] = (short)f2bf((float)((u.y >> 16) & 255));
            f[7] = (short)f2bf((float)(u.y >> 24));
            acnt[kf] = f;
        }
        int xv = xl[rt * 16 + m];
#pragma unroll
        for (int kf = 0; kf < 4; ++kf) {
            int v = xv - kf * 32 - qd * 8;
            short8 f;
#pragma unroll
            for (int j = 0; j < 8; ++j)
                f[j] = (v == j) ? (short)0x3F80 : (short)0;
            aself[kf] = f;
        }
        float iv0 = invd[rt * 16 + qd * 4 + 0];
        float iv1 = invd[rt * 16 + qd * 4 + 1];
        float iv2 = invd[rt * 16 + qd * 4 + 2];
        float iv3 = invd[rt * 16 + qd * 4 + 3];

#pragma unroll
        for (int nt = 0; nt < 4; ++nt) {
            f32x4 accA = {0.f, 0.f, 0.f, 0.f};
            f32x4 accS = {0.f, 0.f, 0.f, 0.f};
#pragma unroll
            for (int kf = 0; kf < 4; ++kf) {
                short8 bA = *(const short8*)(w1frag + ((kf * 4 + nt) * 64 + lane) * 8);
                accA = __builtin_amdgcn_mfma_f32_16x16x32_bf16(acnt[kf], bA, accA, 0, 0, 0);
            }
#pragma unroll
            for (int kf = 0; kf < 4; ++kf) {
                short8 bS = *(const short8*)(w1frag + (((kf + 4) * 4 + nt) * 64 + lane) * 8);
                accS = __builtin_amdgcn_mfma_f32_16x16x32_bf16(aself[kf], bS, accS, 0, 0, 0);
            }
            int c = nt * 16 + m;
            float b1c = b1[c];
            int rb = rt * 16 + qd * 4;
            msbuf[(rb + 0) * 72 + c] = f2bf(fmaxf(accA[0] * iv0 + accS[0] + b1c, 0.f));
            msbuf[(rb + 1) * 72 + c] = f2bf(fmaxf(accA[1] * iv1 + accS[1] + b1c, 0.f));
            msbuf[(rb + 2) * 72 + c] = f2bf(fmaxf(accA[2] * iv2 + accS[2] + b1c, 0.f));
            msbuf[(rb + 3) * 72 + c] = f2bf(fmaxf(accA[3] * iv3 + accS[3] + b1c, 0.f));
        }
    }
    __syncthreads();

#pragma unroll
    for (int rt = wave * 2; rt < wave * 2 + 2; ++rt) {
        const unsigned short* arow = &msbuf[(rt * 16 + m) * 72 + qd * 8];
        short8 a0 = *(const short8*)(arow);
        short8 a1 = *(const short8*)(arow + 32);
        int rowb = nbase + rt * 16 + qd * 4;

#pragma unroll
        for (int tt = 0; tt < 8; ++tt) {
            short8 b0 = *(const short8*)(w2frag + tt * 1024 + lane * 8);
            short8 b1v = *(const short8*)(w2frag + tt * 1024 + 512 + lane * 8);
            f32x4 acc = {0.f, 0.f, 0.f, 0.f};
            acc = __builtin_amdgcn_mfma_f32_16x16x32_bf16(a0, b0, acc, 0, 0, 0);
            acc = __builtin_amdgcn_mfma_f32_16x16x32_bf16(a1, b1v, acc, 0, 0, 0);
            int o = tt * 16 + m;
            if (o < 64) {
                int pk01 = __builtin_amdgcn_cvt_pk_fp8_f32(acc[0], acc[1], 0, false);
                int pk23 = __builtin_amdgcn_cvt_pk_fp8_f32(acc[2], acc[3], 0, false);
                if (rowb + 0 < N_NODES) p8[(rowb + 0) * 64 + o] = (unsigned char)(pk01 & 0xff);
                if (rowb + 1 < N_NODES) p8[(rowb + 1) * 64 + o] = (unsigned char)((pk01 >> 8) & 0xff);
                if (rowb + 2 < N_NODES) p8[(rowb + 2) * 64 + o] = (unsigned char)(pk23 & 0xff);
                if (rowb + 3 < N_NODES) p8[(rowb + 3) * 64 + o] = (unsigned char)((pk23 >> 8) & 0xff);
            } else {
                int oc = o & 63;
#pragma unroll
                for (int i = 0; i < 4; ++i)
                    if (rowb + i < N_NODES)
                        q16[(rowb + i) * 64 + oc] = f2bf(acc[i]);
            }
        }
    }
}

// ---- sage2: asm batched gather from PRE-MASKED col32 (round-12 proven,
//   unchanged; at its random-access memory floor ~54 us).
#define S2_NPW 8
__global__ __launch_bounds__(256) void sage2_kernel(
    const unsigned char* __restrict__ p, const unsigned short* __restrict__ q,
    const int* __restrict__ deg, const int* __restrict__ col32,
    const int2* __restrict__ ovf, const int* __restrict__ ovf_cnt,
    const float* __restrict__ b2,
    const float* __restrict__ Wout, const int* __restrict__ batch,
    float* __restrict__ gsum)
{
    int t = threadIdx.x;
    int wave = t >> 6, lane = t & 63;
    int base_node = (blockIdx.x * 4 + wave) * S2_NPW;   // exact cover
    int c = lane & 15;          // feature quad: features 4c..4c+3
    int g = lane >> 4;          // row group 0..3

    float4 b2v = ((const float4*)b2)[c];
    float4 w01 = ((const float4*)Wout)[c * 2];
    float4 w23 = ((const float4*)Wout)[c * 2 + 1];

    int dgs[S2_NPW];
#pragma unroll
    for (int n = 0; n < S2_NPW; ++n)
        dgs[n] = deg[base_node + n];

#define ACC(a, v) { f32x2 f01_ = __builtin_amdgcn_cvt_pk_f32_fp8((int)(v), false); \
                    f32x2 f23_ = __builtin_amdgcn_cvt_pk_f32_fp8((int)(v), true);  \
                    (a).x += f01_.x; (a).y += f01_.y; (a).z += f23_.x; (a).w += f23_.y; }

#pragma unroll
    for (int hb = 0; hb < 2; ++hb) {
        int nb = hb * 4;                        // nodes base_node+nb .. +nb+3

        // ---- asm block 1: 16 idx loads from col32, offset nn*128 + k*16 ----
        unsigned vc = (unsigned)((base_node + nb) * 128 + g * 4);
        unsigned i00, i01, i02, i03, i10, i11, i12, i13;
        unsigned i20, i21, i22, i23, i30, i31, i32, i33;
        asm volatile(
            "global_load_dword %0,  %16, %17\n\t"
            "global_load_dword %1,  %16, %17 offset:16\n\t"
            "global_load_dword %2,  %16, %17 offset:32\n\t"
            "global_load_dword %3,  %16, %17 offset:48\n\t"
            "global_load_dword %4,  %16, %17 offset:128\n\t"
            "global_load_dword %5,  %16, %17 offset:144\n\t"
            "global_load_dword %6,  %16, %17 offset:160\n\t"
            "global_load_dword %7,  %16, %17 offset:176\n\t"
            "global_load_dword %8,  %16, %17 offset:256\n\t"
            "global_load_dword %9,  %16, %17 offset:272\n\t"
            "global_load_dword %10, %16, %17 offset:288\n\t"
            "global_load_dword %11, %16, %17 offset:304\n\t"
            "global_load_dword %12, %16, %17 offset:384\n\t"
            "global_load_dword %13, %16, %17 offset:400\n\t"
            "global_load_dword %14, %16, %17 offset:416\n\t"
            "global_load_dword %15, %16, %17 offset:432\n\t"
            "s_waitcnt vmcnt(0)"
            : "=&v"(i00), "=&v"(i01), "=&v"(i02), "=&v"(i03),
              "=&v"(i10), "=&v"(i11), "=&v"(i12), "=&v"(i13),
              "=&v"(i20), "=&v"(i21), "=&v"(i22), "=&v"(i23),
              "=&v"(i30), "=&v"(i31), "=&v"(i32), "=&v"(i33)
            : "v"(vc), "s"(col32)
            : "memory");

        // ---- gather byte offsets: idx*64 + c*4 (idx pre-masked/padded) ----
        unsigned cc4 = (unsigned)(c << 2);
        unsigned o00 = (i00 << 6) + cc4, o01 = (i01 << 6) + cc4;
        unsigned o02 = (i02 << 6) + cc4, o03 = (i03 << 6) + cc4;
        unsigned o10 = (i10 << 6) + cc4, o11 = (i11 << 6) + cc4;
        unsigned o12 = (i12 << 6) + cc4, o13 = (i13 << 6) + cc4;
        unsigned o20 = (i20 << 6) + cc4, o21 = (i21 << 6) + cc4;
        unsigned o22 = (i22 << 6) + cc4, o23 = (i23 << 6) + cc4;
        unsigned o30 = (i30 << 6) + cc4, o31 = (i31 << 6) + cc4;
        unsigned o32 = (i32 << 6) + cc4, o33 = (i33 << 6) + cc4;
        unsigned vq = (unsigned)((base_node + nb) * 128 + c * 8);

        // ---- asm block 2: 16 p-gathers + 8 q-dwords, one waitcnt ----
        unsigned v00, v01, v02, v03, v10, v11, v12, v13;
        unsigned v20, v21, v22, v23, v30, v31, v32, v33;
        unsigned qa0, qb0, qa1, qb1, qa2, qb2, qa3, qb3;
        asm volatile(
            "global_load_dword %0,  %24, %41\n\t"
            "global_load_dword %1,  %25, %41\n\t"
            "global_load_dword %2,  %26, %41\n\t"
            "global_load_dword %3,  %27, %41\n\t"
            "global_load_dword %4,  %28, %41\n\t"
            "global_load_dword %5,  %29, %41\n\t"
            "global_load_dword %6,  %30, %41\n\t"
            "global_load_dword %7,  %31, %41\n\t"
            "global_load_dword %8,  %32, %41\n\t"
            "global_load_dword %9,  %33, %41\n\t"
            "global_load_dword %10, %34, %41\n\t"
            "global_load_dword %11, %35, %41\n\t"
            "global_load_dword %12, %36, %41\n\t"
            "global_load_dword %13, %37, %41\n\t"
            "global_load_dword %14, %38, %41\n\t"
            "global_load_dword %15, %39, %41\n\t"
            "global_load_dword %16, %40, %42\n\t"
            "global_load_dword %17, %40, %42 offset:4\n\t"
            "global_load_dword %18, %40, %42 offset:128\n\t"
            "global_load_dword %19, %40, %42 offset:132\n\t"
            "global_load_dword %20, %40, %42 offset:256\n\t"
            "global_load_dword %21, %40, %42 offset:260\n\t"
            "global_load_dword %22, %40, %42 offset:384\n\t"
            "global_load_dword %23, %40, %42 offset:388\n\t"
            "s_waitcnt vmcnt(0)"
            : "=&v"(v00), "=&v"(v01), "=&v"(v02), "=&v"(v03),
              "=&v"(v10), "=&v"(v11), "=&v"(v12), "=&v"(v13),
              "=&v"(v20), "=&v"(v21), "=&v"(v22), "=&v"(v23),
              "=&v"(v30), "=&v"(v31), "=&v"(v32), "=&v"(v33),
              "=&v"(qa0), "=&v"(qb0), "=&v"(qa1), "=&v"(qb1),
              "=&v"(qa2), "=&v"(qb2), "=&v"(qa3), "=&v"(qb3)
            : "v"(o00), "v"(o01), "v"(o02), "v"(o03),
              "v"(o10), "v"(o11), "v"(o12), "v"(o13),
              "v"(o20), "v"(o21), "v"(o22), "v"(o23),
              "v"(o30), "v"(o31), "v"(o32), "v"(o33),
              "v"(vq), "s"(p), "s"(q)
            : "memory");

        // ---- consume the two pairs of this batch ----
#pragma unroll
        for (int pp = 0; pp < 2; ++pp) {
            int na = nb + pp * 2, nbd = nb + pp * 2 + 1;
            int dgA = dgs[na], dgB = dgs[nbd];
            int nodeA = base_node + na, nodeB = base_node + nbd;

            float4 aA = {0.f,0.f,0.f,0.f}, aB = {0.f,0.f,0.f,0.f};
            if (pp == 0) {
                ACC(aA, v00) ACC(aA, v01) ACC(aA, v02) ACC(aA, v03)
                ACC(aB, v10) ACC(aB, v11) ACC(aB, v12) ACC(aB, v13)
            } else {
                ACC(aA, v20) ACC(aA, v21) ACC(aA, v22) ACC(aA, v23)
                ACC(aB, v30) ACC(aB, v31) ACC(aB, v32) ACC(aB, v33)
            }

            // --- deg>16 tail: direct col32 slot loads (pre-masked, rare) ---
            if (dgA > 16) {
                for (int j = 16; j < 32; j += 8) {
                    unsigned i0 = (unsigned)col32[(size_t)nodeA * 32 + j + g];
                    unsigned i1 = (unsigned)col32[(size_t)nodeA * 32 + j + 4 + g];
                    unsigned u0 = *(const unsigned*)(p + ((size_t)i0 << 6) + c * 4);
                    unsigned u1 = *(const unsigned*)(p + ((size_t)i1 << 6) + c * 4);
                    ACC(aA, u0) ACC(aA, u1)
                }
                if (dgA > 32) {                          // overflow fallback (~never)
                    int ovn = *ovf_cnt; if (ovn > OVF_CAP) ovn = OVF_CAP;
                    for (int k = 0; k < ovn; ++k) {
                        int2 e = ovf[k];
                        if (e.x == nodeA) {
                            unsigned i_ = (unsigned)e.y & 0x1FFFFu;
                            unsigned u = *(const unsigned*)(p + ((size_t)i_ << 6) + c * 4);
                            if (g == 0) ACC(aA, u)
                        }
                    }
                }
            }
            if (dgB > 16) {
                for (int j = 16; j < 32; j += 8) {
                    unsigned i0 = (unsigned)col32[(size_t)nodeB * 32 + j + g];
                    unsigned i1 = (unsigned)col32[(size_t)nodeB * 32 + j + 4 + g];
                    unsigned u0 = *(const unsigned*)(p + ((size_t)i0 << 6) + c * 4);
                    unsigned u1 = *(const unsigned*)(p + ((size_t)i1 << 6) + c * 4);
                    ACC(aB, u0) ACC(aB, u1)
                }
                if (dgB > 32) {
                    int ovn = *ovf_cnt; if (ovn > OVF_CAP) ovn = OVF_CAP;
                    for (int k = 0; k < ovn; ++k) {
                        int2 e = ovf[k];
                        if (e.x == nodeB) {
                            unsigned i_ = (unsigned)e.y & 0x1FFFFu;
                            unsigned u = *(const unsigned*)(p + ((size_t)i_ << 6) + c * 4);
                            if (g == 0) ACC(aB, u)
                        }
                    }
                }
            }

            // --- cross-group reduce ---
            aA.x += __shfl_xor(aA.x, 16, 64); aA.y += __shfl_xor(aA.y, 16, 64);
            aA.z += __shfl_xor(aA.z, 16, 64); aA.w += __shfl_xor(aA.w, 16, 64);
            aB.x += __shfl_xor(aB.x, 16, 64); aB.y += __shfl_xor(aB.y, 16, 64);
            aB.z += __shfl_xor(aB.z, 16, 64); aB.w += __shfl_xor(aB.w, 16, 64);
            aA.x += __shfl_xor(aA.x, 32, 64); aA.y += __shfl_xor(aA.y, 32, 64);
            aA.z += __shfl_xor(aA.z, 32, 64); aA.w += __shfl_xor(aA.w, 32, 64);
            aB.x += __shfl_xor(aB.x, 32, 64); aB.y += __shfl_xor(aB.y, 32, 64);
            aB.z += __shfl_xor(aB.z, 32, 64); aB.w += __shfl_xor(aB.w, 32, 64);

            // --- epilogue for both nodes ---
#pragma unroll
            for (int e = 0; e < 2; ++e) {
                int node = base_node + nb + pp * 2 + e;
                int dg = (e == 0) ? dgA : dgB;
                float4 a = (e == 0) ? aA : aB;
                int li = pp * 2 + e;
                unsigned qlo = (li == 0) ? qa0 : (li == 1) ? qa1 : (li == 2) ? qa2 : qa3;
                unsigned qhi = (li == 0) ? qb0 : (li == 1) ? qb1 : (li == 2) ? qb2 : qb3;
                float inv = 1.0f / fmaxf((float)dg, 1.0f);
                float h0 = fmaxf(a.x * inv + b2v.x + bf2f_lo(qlo), 0.f);
                float h1 = fmaxf(a.y * inv + b2v.y + bf2f_hi(qlo), 0.f);
                float h2 = fmaxf(a.z * inv + b2v.z + bf2f_lo(qhi), 0.f);
                float h3 = fmaxf(a.w * inv + b2v.w + bf2f_hi(qhi), 0.f);

                float p0 = h0 * w01.x + h1 * w01.z + h2 * w23.x + h3 * w23.z;
                float p1 = h0 * w01.y + h1 * w01.w + h2 * w23.y + h3 * w23.w;
                if (g != 0) { p0 = 0.f; p1 = 0.f; }     // groups duplicate
                p0 += __shfl_down(p0, 8, 64);  p1 += __shfl_down(p1, 8, 64);
                p0 += __shfl_down(p0, 4, 64);  p1 += __shfl_down(p1, 4, 64);
                p0 += __shfl_down(p0, 2, 64);  p1 += __shfl_down(p1, 2, 64);
                p0 += __shfl_down(p0, 1, 64);  p1 += __shfl_down(p1, 1, 64);
                if (lane == 0) {
                    int grp = batch[node];
                    atomicAdd(&gsum[grp * 2 + 0], p0);
                    atomicAdd(&gsum[grp * 2 + 1], p1);
                }
            }
        }
    }
#undef ACC
}

// ---------------- finalize: out = gsum/cnt + bout ----------------
__global__ __launch_bounds__(256) void finalize_kernel(
    const float* __restrict__ gsum, const int* __restrict__ gstart,
    const float* __restrict__ bout, float* __restrict__ out)
{
    int g = blockIdx.x * 256 + threadIdx.x;
    if (g >= N_GRAPHS) return;
    int cnt = gstart[g + 1] - gstart[g];
    float inv = 1.0f / fmaxf((float)cnt, 1.0f);
    out[g * 2 + 0] = gsum[g * 2 + 0] * inv + bout[0];
    out[g * 2 + 1] = gsum[g * 2 + 1] * inv + bout[1];
}

extern "C" void kernel_launch(void* const* d_in, const int* in_sizes, int n_in,
                              void* d_out, int out_size, void* d_ws, size_t ws_size,
                              hipStream_t stream) {
    const int*   x    = (const int*)  d_in[0];
    const int*   ei   = (const int*)  d_in[1];
    const int*   batch= (const int*)  d_in[2];
    const float* emb  = (const float*)d_in[3];
    const float* W1l  = (const float*)d_in[4];
    const float* b1   = (const float*)d_in[5];
    const float* W1r  = (const float*)d_in[6];
    const float* W2l  = (const float*)d_in[7];
    const float* b2   = (const float*)d_in[8];
    const float* W2r  = (const float*)d_in[9];
    const float* Wout = (const float*)d_in[10];
    const float* bout = (const float*)d_in[11];
    float* out = (float*)d_out;

    const int* src = ei;
    const int* dst = ei + N_EDGES;

    char* ws = (char*)d_ws;
    size_t off = 0;
    unsigned char*  p8     = (unsigned char*) (ws + off); off += (size_t)(ZROW + 1) * 64;   // 8.39 MB (dummy row at ZROW)
    unsigned short* q16    = (unsigned short*)(ws + off); off += (size_t)N_NODES * 64 * 2;  // 12.8 MB
    unsigned short* w2frag = (unsigned short*)(ws + off); off += (size_t)8192 * 2;
    unsigned short* w1frag = (unsigned short*)(ws + off); off += (size_t)16384 * 2;         // 32 KB
    int*      col32  = (int*)     (ws + off); off += (size_t)NPAD * 32 * 4;                 // 12.8 MB
    int2*     ovf    = (int2*)    (ws + off); off += (size_t)OVF_CAP * 8;                   // 512 KB
    unsigned* edge8  = (unsigned*)(ws + off); off += (size_t)NBK * CAP * 4;                 // 6.4 MB
    int*      dcnt   = (int*)     (ws + off); off += (size_t)NPAD * 4;                      // written by sage1
    int*      gstart = (int*)     (ws + off); off += (size_t)(N_GRAPHS + 2) * 4;
    // contiguous zero region: cursor (strided x16) | ovf_cnt | gsum (one memset)
    int*      cursor = (int*)     (ws + off); off += (size_t)NBK * 16 * 4;                  // 25 KB
    int*      ovfcnt = (int*)     (ws + off); off += (size_t)4;
    float*    gsum   = (float*)   (ws + off); off += (size_t)N_GRAPHS * 2 * 4;

    hipMemsetAsync(cursor, 0, (size_t)NBK * 16 * 4 + 4 + (size_t)N_GRAPHS * 2 * 4, stream);

    scatter_kernel<<<SCAT_BLOCKS + GB + 32, 1024, 0, stream>>>(
        src, dst, x, cursor, edge8,
        batch, gstart, emb, W1l, W1r, W2l, W2r, w1frag, w2frag, p8);
    sage1_kernel<<<NBK * 2, 256, 0, stream>>>(
        x, edge8, cursor, dcnt, col32, ovf, ovfcnt,
        w1frag, w2frag, b1, p8, q16);
    sage2_kernel<<<N_NODES / (4 * S2_NPW), 256, 0, stream>>>(
        p8, q16, dcnt, col32, ovf, ovfcnt, b2, Wout, batch, gsum);
    finalize_kernel<<<(N_GRAPHS + 255) / 256, 256, 0, stream>>>(gsum, gstart, bout, out);
}